// Round 1
// baseline (3549.479 us; speedup 1.0000x reference)
//
#include <hip/hip_runtime.h>
#include <hip/hip_bf16.h>
#include <cstdint>
#include <cstddef>

#define IN_F 128
#define HID 128
#define NH1 4
#define OUTF 64

__device__ __forceinline__ unsigned enc_f(float f) {
  unsigned u = __float_as_uint(f);
  return (u & 0x80000000u) ? ~u : (u | 0x80000000u);
}
__device__ __forceinline__ float dec_f(unsigned u) {
  return __uint_as_float((u & 0x80000000u) ? (u ^ 0x80000000u) : ~u);
}
__device__ __forceinline__ float lrelu(float v) { return v > 0.f ? v : 0.2f * v; }
__device__ __forceinline__ float eluf(float v) { return v > 0.f ? v : (__expf(v) - 1.f); }

// ---------------------------------------------------------------- init
__global__ void k_init(unsigned* __restrict__ m1u, float* __restrict__ s1,
                       unsigned* __restrict__ m2u, float* __restrict__ s2,
                       float* __restrict__ out1, const float* __restrict__ b1,
                       float* __restrict__ out2, const float* __restrict__ b2, int N) {
  int t = blockIdx.x * blockDim.x + threadIdx.x;
  if (t < N * NH1) { m1u[t] = 0x007FFFFFu; s1[t] = 0.f; }  // enc(-inf)
  if (t < N)       { m2u[t] = 0x007FFFFFu; s2[t] = 0.f; }
  if (t < N * HID)  out1[t] = b1[t & (HID - 1)];
  if (t < N * OUTF) out2[t] = b2[t & (OUTF - 1)];
}

// ---------------------------------------------------------------- layer-1 GEMM + attention dots
// block = 256 (4 waves). Each wave processes 4 consecutive rows; lane handles cols (lane, lane+64).
__global__ __launch_bounds__(256) void k_gemm1(
    const float* __restrict__ x, const float* __restrict__ W,
    const float* __restrict__ a_s, const float* __restrict__ a_d,
    float* __restrict__ h, float* __restrict__ als, float* __restrict__ ald, int N) {
  __shared__ float xs[4][4 * IN_F];
  const int wave = threadIdx.x >> 6, lane = threadIdx.x & 63;
  const float as0 = a_s[lane], as1 = a_s[lane + 64];
  const float ad0 = a_d[lane], ad1 = a_d[lane + 64];
  const int stride = gridDim.x * 16;
  for (int base = blockIdx.x * 16; base < N; base += stride) {
    const int r0 = base + wave * 4;
    const int vr = max(0, min(4, N - r0));
    float* xw = xs[wave];
    __syncthreads();
    if (vr == 4) {
      const float4* xp = (const float4*)(x + (size_t)r0 * IN_F);
      *(float4*)(xw + lane * 4) = xp[lane];
      *(float4*)(xw + 256 + lane * 4) = xp[64 + lane];
    } else if (vr > 0) {
      for (int i = lane; i < vr * IN_F; i += 64) xw[i] = x[(size_t)r0 * IN_F + i];
    }
    __syncthreads();
    if (vr > 0) {
      float acc[4][2] = {{0.f,0.f},{0.f,0.f},{0.f,0.f},{0.f,0.f}};
      for (int k = 0; k < IN_F; k += 4) {
        float4 xr[4];
        #pragma unroll
        for (int ri = 0; ri < 4; ++ri) xr[ri] = *(const float4*)(xw + ri * IN_F + k);
        #pragma unroll
        for (int kk = 0; kk < 4; ++kk) {
          const float w0 = W[(k + kk) * HID + lane];
          const float w1 = W[(k + kk) * HID + lane + 64];
          #pragma unroll
          for (int ri = 0; ri < 4; ++ri) {
            const float xv = ((const float*)&xr[ri])[kk];
            acc[ri][0] += xv * w0;
            acc[ri][1] += xv * w1;
          }
        }
      }
      #pragma unroll
      for (int ri = 0; ri < 4; ++ri) {
        if (ri < vr) {
          const int r = r0 + ri;
          h[(size_t)r * HID + lane]      = acc[ri][0];
          h[(size_t)r * HID + lane + 64] = acc[ri][1];
        }
      }
      #pragma unroll
      for (int ri = 0; ri < 4; ++ri) {
        float ps0 = acc[ri][0] * as0, pd0 = acc[ri][0] * ad0;
        float ps1 = acc[ri][1] * as1, pd1 = acc[ri][1] * ad1;
        #pragma unroll
        for (int m = 16; m >= 1; m >>= 1) {
          ps0 += __shfl_xor(ps0, m, 32); pd0 += __shfl_xor(pd0, m, 32);
          ps1 += __shfl_xor(ps1, m, 32); pd1 += __shfl_xor(pd1, m, 32);
        }
        if (ri < vr && (lane & 31) == 0) {
          const int r = r0 + ri, hh = lane >> 5;
          als[r * NH1 + hh]     = ps0;  ald[r * NH1 + hh]     = pd0;
          als[r * NH1 + 2 + hh] = ps1;  ald[r * NH1 + 2 + hh] = pd1;
        }
      }
    }
  }
}

// ---------------------------------------------------------------- layer-2 GEMM (ELU fused on load)
__global__ __launch_bounds__(256) void k_gemm2(
    const float* __restrict__ hin, const float* __restrict__ W,
    const float* __restrict__ a_s, const float* __restrict__ a_d,
    float* __restrict__ h, float* __restrict__ als, float* __restrict__ ald, int N) {
  __shared__ float xs[4][4 * HID];
  const int wave = threadIdx.x >> 6, lane = threadIdx.x & 63;
  const float asj = a_s[lane], adj = a_d[lane];
  const int stride = gridDim.x * 16;
  for (int base = blockIdx.x * 16; base < N; base += stride) {
    const int r0 = base + wave * 4;
    const int vr = max(0, min(4, N - r0));
    float* xw = xs[wave];
    __syncthreads();
    if (vr == 4) {
      const float4* xp = (const float4*)(hin + (size_t)r0 * HID);
      float4 v0 = xp[lane], v1 = xp[64 + lane];
      v0.x = eluf(v0.x); v0.y = eluf(v0.y); v0.z = eluf(v0.z); v0.w = eluf(v0.w);
      v1.x = eluf(v1.x); v1.y = eluf(v1.y); v1.z = eluf(v1.z); v1.w = eluf(v1.w);
      *(float4*)(xw + lane * 4) = v0;
      *(float4*)(xw + 256 + lane * 4) = v1;
    } else if (vr > 0) {
      for (int i = lane; i < vr * HID; i += 64) xw[i] = eluf(hin[(size_t)r0 * HID + i]);
    }
    __syncthreads();
    if (vr > 0) {
      float acc[4] = {0.f, 0.f, 0.f, 0.f};
      for (int k = 0; k < HID; k += 4) {
        float4 xr[4];
        #pragma unroll
        for (int ri = 0; ri < 4; ++ri) xr[ri] = *(const float4*)(xw + ri * HID + k);
        #pragma unroll
        for (int kk = 0; kk < 4; ++kk) {
          const float w0 = W[(k + kk) * OUTF + lane];
          #pragma unroll
          for (int ri = 0; ri < 4; ++ri) acc[ri] += ((const float*)&xr[ri])[kk] * w0;
        }
      }
      #pragma unroll
      for (int ri = 0; ri < 4; ++ri) {
        if (ri < vr) h[(size_t)(r0 + ri) * OUTF + lane] = acc[ri];
      }
      #pragma unroll
      for (int ri = 0; ri < 4; ++ri) {
        float ps = acc[ri] * asj, pd = acc[ri] * adj;
        #pragma unroll
        for (int m = 32; m >= 1; m >>= 1) {
          ps += __shfl_xor(ps, m, 64); pd += __shfl_xor(pd, m, 64);
        }
        if (ri < vr && lane == 0) { als[r0 + ri] = ps; ald[r0 + ri] = pd; }
      }
    }
  }
}

// ---------------------------------------------------------------- edge softmax: max
template <int H>
__global__ void k_edge_max(const int* __restrict__ src, const int* __restrict__ dst,
                           int E, int N,
                           const float* __restrict__ als, const float* __restrict__ ald,
                           unsigned* __restrict__ mu) {
  const int t = blockIdx.x * blockDim.x + threadIdx.x;
  const int total = (E + N) * H;
  if (t >= total) return;
  const int e = t / H, h = t - e * H;
  int s, d;
  if (e < E) { s = src[e]; d = dst[e]; } else { s = d = e - E; }
  const float v = lrelu(als[s * H + h] + ald[d * H + h]);
  atomicMax(mu + d * H + h, enc_f(v));
}

// ---------------------------------------------------------------- edge softmax: denom
template <int H>
__global__ void k_edge_sum(const int* __restrict__ src, const int* __restrict__ dst,
                           int E, int N,
                           const float* __restrict__ als, const float* __restrict__ ald,
                           const unsigned* __restrict__ mu, float* __restrict__ ssum) {
  const int t = blockIdx.x * blockDim.x + threadIdx.x;
  const int total = (E + N) * H;
  if (t >= total) return;
  const int e = t / H, h = t - e * H;
  int s, d;
  if (e < E) { s = src[e]; d = dst[e]; } else { s = d = e - E; }
  const float v = lrelu(als[s * H + h] + ald[d * H + h]);
  const float m = dec_f(mu[d * H + h]);
  atomicAdd(ssum + d * H + h, __expf(v - m));
}

// ---------------------------------------------------------------- weighted aggregation
// one thread per (edge, feature-quad); 32 (or 16) consecutive threads share an edge.
template <int H, int C>
__global__ void k_edge_aggr(const int* __restrict__ src, const int* __restrict__ dst,
                            int E, int N,
                            const float* __restrict__ als, const float* __restrict__ ald,
                            const unsigned* __restrict__ mu, const float* __restrict__ ssum,
                            const float* __restrict__ hfeat, float* __restrict__ out) {
  const int F = H * C, QP = F / 4;
  const long long t = (long long)blockIdx.x * blockDim.x + threadIdx.x;
  if (t >= (long long)(E + N) * QP) return;
  const int e = (int)(t / QP);
  const int q = (int)(t - (long long)e * QP);
  int s, d;
  if (e < E) { s = src[e]; d = dst[e]; } else { s = d = e - E; }
  const int j = q * 4;
  const int head = j / C;
  const float v = lrelu(als[s * H + head] + ald[d * H + head]);
  const float alpha = __expf(v - dec_f(mu[d * H + head])) / (ssum[d * H + head] + 1e-16f);
  const float4 hv = *(const float4*)(hfeat + (size_t)s * F + j);
  float* op = out + (size_t)d * F + j;
  atomicAdd(op + 0, alpha * hv.x);
  atomicAdd(op + 1, alpha * hv.y);
  atomicAdd(op + 2, alpha * hv.z);
  atomicAdd(op + 3, alpha * hv.w);
}

// ---------------------------------------------------------------- launch
extern "C" void kernel_launch(void* const* d_in, const int* in_sizes, int n_in,
                              void* d_out, int out_size, void* d_ws, size_t ws_size,
                              hipStream_t stream) {
  const float* x   = (const float*)d_in[0];
  const int*   ei  = (const int*)d_in[1];
  const float* W1  = (const float*)d_in[2];
  const float* a1s = (const float*)d_in[3];
  const float* a1d = (const float*)d_in[4];
  const float* b1  = (const float*)d_in[5];
  const float* W2  = (const float*)d_in[6];
  const float* a2s = (const float*)d_in[7];
  const float* a2d = (const float*)d_in[8];
  const float* b2  = (const float*)d_in[9];
  float* out = (float*)d_out;

  const int N = in_sizes[0] / IN_F;
  const int E = in_sizes[1] / 2;
  const int ET = E + N;
  const int* srcI = ei;
  const int* dstI = ei + E;

  float* ws = (float*)d_ws;
  float* h1    = ws;                          // N*128 floats (reused as h2: N*64)
  float* out1  = h1 + (size_t)N * HID;        // N*128
  float* al1s_ = out1 + (size_t)N * HID;      // N*4
  float* al1d_ = al1s_ + (size_t)N * NH1;     // N*4
  float* s1    = al1d_ + (size_t)N * NH1;     // N*4
  unsigned* m1u = (unsigned*)(s1 + (size_t)N * NH1);   // N*4
  float* al2s_ = (float*)(m1u + (size_t)N * NH1);      // N
  float* al2d_ = al2s_ + N;                   // N
  float* s2    = al2d_ + N;                   // N
  unsigned* m2u = (unsigned*)(s2 + N);        // N

  // phase 0: init accumulators (bias pre-loaded into outputs)
  {
    int total = N * HID;
    k_init<<<(total + 255) / 256, 256, 0, stream>>>(m1u, s1, m2u, s2, out1, b1, out, b2, N);
  }
  // layer 1
  k_gemm1<<<512, 256, 0, stream>>>(x, W1, a1s, a1d, h1, al1s_, al1d_, N);
  k_edge_max<NH1><<<((size_t)ET * NH1 + 255) / 256, 256, 0, stream>>>(srcI, dstI, E, N, al1s_, al1d_, m1u);
  k_edge_sum<NH1><<<((size_t)ET * NH1 + 255) / 256, 256, 0, stream>>>(srcI, dstI, E, N, al1s_, al1d_, m1u, s1);
  k_edge_aggr<NH1, 32><<<((size_t)ET * 32 + 255) / 256, 256, 0, stream>>>(
      srcI, dstI, E, N, al1s_, al1d_, m1u, s1, h1, out1);
  // layer 2 (h2 aliases h1's buffer)
  k_gemm2<<<1024, 256, 0, stream>>>(out1, W2, a2s, a2d, h1, al2s_, al2d_, N);
  k_edge_max<1><<<((size_t)ET + 255) / 256, 256, 0, stream>>>(srcI, dstI, E, N, al2s_, al2d_, m2u);
  k_edge_sum<1><<<((size_t)ET + 255) / 256, 256, 0, stream>>>(srcI, dstI, E, N, al2s_, al2d_, m2u, s2);
  k_edge_aggr<1, OUTF><<<((size_t)ET * (OUTF / 4) + 255) / 256, 256, 0, stream>>>(
      srcI, dstI, E, N, al2s_, al2d_, m2u, s2, h1, out);
}

// Round 2
// 1696.074 us; speedup vs baseline: 2.0928x; 2.0928x over previous
//
#include <hip/hip_runtime.h>
#include <hip/hip_bf16.h>
#include <cstdint>
#include <cstddef>

#define IN_F 128
#define HID 128
#define NH1 4
#define OUTF 64

__device__ __forceinline__ float lrelu(float v) { return v > 0.f ? v : 0.2f * v; }
__device__ __forceinline__ float eluf(float v) { return v > 0.f ? v : (__expf(v) - 1.f); }

// ---------------------------------------------------------------- CSR build
__global__ void k_counts_init(int* __restrict__ counts, int N) {
  int t = blockIdx.x * blockDim.x + threadIdx.x;
  if (t < N) counts[t] = 1;  // self-loop
}

__global__ void k_count(const int* __restrict__ dst, int E, int* __restrict__ counts) {
  int e = blockIdx.x * blockDim.x + threadIdx.x;
  if (e < E) atomicAdd(counts + dst[e], 1);
}

// single-block exclusive scan over N counts -> rowptr; also seed cursor & self-loop entry
__global__ __launch_bounds__(1024) void k_scan(const int* __restrict__ counts,
                                               int* __restrict__ rowptr,
                                               int* __restrict__ cursor,
                                               int* __restrict__ csr, int N) {
  __shared__ int sums[1024];
  const int t = threadIdx.x;
  const int chunk = (N + 1023) / 1024;
  const int lo = t * chunk, hi = min(N, lo + chunk);
  int s = 0;
  for (int i = lo; i < hi; ++i) s += counts[i];
  sums[t] = s;
  __syncthreads();
  for (int off = 1; off < 1024; off <<= 1) {
    int v = (t >= off) ? sums[t - off] : 0;
    __syncthreads();
    sums[t] += v;
    __syncthreads();
  }
  int excl = (t == 0) ? 0 : sums[t - 1];
  for (int i = lo; i < hi; ++i) {
    rowptr[i] = excl;
    cursor[i] = excl + 1;   // slot 0 reserved for self-loop
    csr[excl] = i;          // self-loop src = i
    excl += counts[i];
  }
}

__global__ void k_scatter(const int* __restrict__ src, const int* __restrict__ dst, int E,
                          int* __restrict__ cursor, int* __restrict__ csr) {
  int e = blockIdx.x * blockDim.x + threadIdx.x;
  if (e < E) {
    int d = dst[e];
    int pos = atomicAdd(cursor + d, 1);
    csr[pos] = src[e];
  }
}

// ---------------------------------------------------------------- layer-1 GEMM + attention dots
__global__ __launch_bounds__(256) void k_gemm1(
    const float* __restrict__ x, const float* __restrict__ W,
    const float* __restrict__ a_s, const float* __restrict__ a_d,
    float* __restrict__ h, float* __restrict__ als, float* __restrict__ ald, int N) {
  __shared__ float xs[4][4 * IN_F];
  const int wave = threadIdx.x >> 6, lane = threadIdx.x & 63;
  const float as0 = a_s[lane], as1 = a_s[lane + 64];
  const float ad0 = a_d[lane], ad1 = a_d[lane + 64];
  const int stride = gridDim.x * 16;
  for (int base = blockIdx.x * 16; base < N; base += stride) {
    const int r0 = base + wave * 4;
    const int vr = max(0, min(4, N - r0));
    float* xw = xs[wave];
    __syncthreads();
    if (vr == 4) {
      const float4* xp = (const float4*)(x + (size_t)r0 * IN_F);
      *(float4*)(xw + lane * 4) = xp[lane];
      *(float4*)(xw + 256 + lane * 4) = xp[64 + lane];
    } else if (vr > 0) {
      for (int i = lane; i < vr * IN_F; i += 64) xw[i] = x[(size_t)r0 * IN_F + i];
    }
    __syncthreads();
    if (vr > 0) {
      float acc[4][2] = {{0.f,0.f},{0.f,0.f},{0.f,0.f},{0.f,0.f}};
      for (int k = 0; k < IN_F; k += 4) {
        float4 xr[4];
        #pragma unroll
        for (int ri = 0; ri < 4; ++ri) xr[ri] = *(const float4*)(xw + ri * IN_F + k);
        #pragma unroll
        for (int kk = 0; kk < 4; ++kk) {
          const float w0 = W[(k + kk) * HID + lane];
          const float w1 = W[(k + kk) * HID + lane + 64];
          #pragma unroll
          for (int ri = 0; ri < 4; ++ri) {
            const float xv = ((const float*)&xr[ri])[kk];
            acc[ri][0] += xv * w0;
            acc[ri][1] += xv * w1;
          }
        }
      }
      #pragma unroll
      for (int ri = 0; ri < 4; ++ri) {
        if (ri < vr) {
          const int r = r0 + ri;
          h[(size_t)r * HID + lane]      = acc[ri][0];
          h[(size_t)r * HID + lane + 64] = acc[ri][1];
        }
      }
      #pragma unroll
      for (int ri = 0; ri < 4; ++ri) {
        float ps0 = acc[ri][0] * as0, pd0 = acc[ri][0] * ad0;
        float ps1 = acc[ri][1] * as1, pd1 = acc[ri][1] * ad1;
        #pragma unroll
        for (int m = 16; m >= 1; m >>= 1) {
          ps0 += __shfl_xor(ps0, m, 32); pd0 += __shfl_xor(pd0, m, 32);
          ps1 += __shfl_xor(ps1, m, 32); pd1 += __shfl_xor(pd1, m, 32);
        }
        if (ri < vr && (lane & 31) == 0) {
          const int r = r0 + ri, hh = lane >> 5;
          als[r * NH1 + hh]     = ps0;  ald[r * NH1 + hh]     = pd0;
          als[r * NH1 + 2 + hh] = ps1;  ald[r * NH1 + 2 + hh] = pd1;
        }
      }
    }
  }
}

// ---------------------------------------------------------------- layer-2 GEMM (ELU fused on load)
__global__ __launch_bounds__(256) void k_gemm2(
    const float* __restrict__ hin, const float* __restrict__ W,
    const float* __restrict__ a_s, const float* __restrict__ a_d,
    float* __restrict__ h, float* __restrict__ als, float* __restrict__ ald, int N) {
  __shared__ float xs[4][4 * HID];
  const int wave = threadIdx.x >> 6, lane = threadIdx.x & 63;
  const float asj = a_s[lane], adj = a_d[lane];
  const int stride = gridDim.x * 16;
  for (int base = blockIdx.x * 16; base < N; base += stride) {
    const int r0 = base + wave * 4;
    const int vr = max(0, min(4, N - r0));
    float* xw = xs[wave];
    __syncthreads();
    if (vr == 4) {
      const float4* xp = (const float4*)(hin + (size_t)r0 * HID);
      float4 v0 = xp[lane], v1 = xp[64 + lane];
      v0.x = eluf(v0.x); v0.y = eluf(v0.y); v0.z = eluf(v0.z); v0.w = eluf(v0.w);
      v1.x = eluf(v1.x); v1.y = eluf(v1.y); v1.z = eluf(v1.z); v1.w = eluf(v1.w);
      *(float4*)(xw + lane * 4) = v0;
      *(float4*)(xw + 256 + lane * 4) = v1;
    } else if (vr > 0) {
      for (int i = lane; i < vr * HID; i += 64) xw[i] = eluf(hin[(size_t)r0 * HID + i]);
    }
    __syncthreads();
    if (vr > 0) {
      float acc[4] = {0.f, 0.f, 0.f, 0.f};
      for (int k = 0; k < HID; k += 4) {
        float4 xr[4];
        #pragma unroll
        for (int ri = 0; ri < 4; ++ri) xr[ri] = *(const float4*)(xw + ri * HID + k);
        #pragma unroll
        for (int kk = 0; kk < 4; ++kk) {
          const float w0 = W[(k + kk) * OUTF + lane];
          #pragma unroll
          for (int ri = 0; ri < 4; ++ri) acc[ri] += ((const float*)&xr[ri])[kk] * w0;
        }
      }
      #pragma unroll
      for (int ri = 0; ri < 4; ++ri) {
        if (ri < vr) h[(size_t)(r0 + ri) * OUTF + lane] = acc[ri];
      }
      #pragma unroll
      for (int ri = 0; ri < 4; ++ri) {
        float ps = acc[ri] * asj, pd = acc[ri] * adj;
        #pragma unroll
        for (int m = 32; m >= 1; m >>= 1) {
          ps += __shfl_xor(ps, m, 64); pd += __shfl_xor(pd, m, 64);
        }
        if (ri < vr && lane == 0) { als[r0 + ri] = ps; ald[r0 + ri] = pd; }
      }
    }
  }
}

// ---------------------------------------------------------------- gather softmax+aggregation, layer 1
// one block (128 thr) per dst node; lane j owns feature j; head = j>>5
__global__ __launch_bounds__(128) void k_aggr1(
    const int* __restrict__ rowptr, const int* __restrict__ counts,
    const int* __restrict__ csr,
    const float* __restrict__ als, const float* __restrict__ ald,
    const float* __restrict__ h, const float* __restrict__ b,
    float* __restrict__ out, int N) {
  const int d = blockIdx.x;
  if (d >= N) return;
  const int j = threadIdx.x;
  const int head = j >> 5;
  const int row0 = rowptr[d];
  const int deg = counts[d];
  const float aldh = ald[d * NH1 + head];
  float m = -1e30f;
  for (int i = 0; i < deg; ++i) {
    const int s = csr[row0 + i];
    const float v = lrelu(als[s * NH1 + head] + aldh);
    m = fmaxf(m, v);
  }
  float sum = 0.f, acc = 0.f;
  for (int i = 0; i < deg; ++i) {
    const int s = csr[row0 + i];
    const float v = lrelu(als[s * NH1 + head] + aldh);
    const float p = __expf(v - m);
    sum += p;
    acc += p * h[(size_t)s * HID + j];
  }
  out[(size_t)d * HID + j] = acc / (sum + 1e-16f) + b[j];
}

// ---------------------------------------------------------------- gather softmax+aggregation, layer 2
// one block (64 thr) per dst node; H=1, C=64
__global__ __launch_bounds__(64) void k_aggr2(
    const int* __restrict__ rowptr, const int* __restrict__ counts,
    const int* __restrict__ csr,
    const float* __restrict__ als, const float* __restrict__ ald,
    const float* __restrict__ h, const float* __restrict__ b,
    float* __restrict__ out, int N) {
  const int d = blockIdx.x;
  if (d >= N) return;
  const int j = threadIdx.x;
  const int row0 = rowptr[d];
  const int deg = counts[d];
  const float aldd = ald[d];
  float m = -1e30f;
  for (int i = 0; i < deg; ++i) {
    const int s = csr[row0 + i];
    const float v = lrelu(als[s] + aldd);
    m = fmaxf(m, v);
  }
  float sum = 0.f, acc = 0.f;
  for (int i = 0; i < deg; ++i) {
    const int s = csr[row0 + i];
    const float v = lrelu(als[s] + aldd);
    const float p = __expf(v - m);
    sum += p;
    acc += p * h[(size_t)s * OUTF + j];
  }
  out[(size_t)d * OUTF + j] = acc / (sum + 1e-16f) + b[j];
}

// ---------------------------------------------------------------- launch
extern "C" void kernel_launch(void* const* d_in, const int* in_sizes, int n_in,
                              void* d_out, int out_size, void* d_ws, size_t ws_size,
                              hipStream_t stream) {
  const float* x   = (const float*)d_in[0];
  const int*   ei  = (const int*)d_in[1];
  const float* W1  = (const float*)d_in[2];
  const float* a1s = (const float*)d_in[3];
  const float* a1d = (const float*)d_in[4];
  const float* b1  = (const float*)d_in[5];
  const float* W2  = (const float*)d_in[6];
  const float* a2s = (const float*)d_in[7];
  const float* a2d = (const float*)d_in[8];
  const float* b2  = (const float*)d_in[9];
  float* out = (float*)d_out;

  const int N = in_sizes[0] / IN_F;
  const int E = in_sizes[1] / 2;
  const int* srcI = ei;
  const int* dstI = ei + E;

  // workspace layout (ints first, then 16B-aligned floats)
  int* rowptr = (int*)d_ws;                   // N
  int* counts = rowptr + N;                   // N
  int* cursor = counts + N;                   // N
  int* csr    = cursor + N;                   // E+N
  size_t int_end = (size_t)(3 * N + E + N);
  int_end = (int_end + 3) & ~(size_t)3;       // 16B alignment for float4
  float* h1    = (float*)d_ws + int_end;      // N*128 (reused as h2: N*64)
  float* out1  = h1 + (size_t)N * HID;        // N*128
  float* al1s_ = out1 + (size_t)N * HID;      // N*4
  float* al1d_ = al1s_ + (size_t)N * NH1;     // N*4
  float* al2s_ = al1d_ + (size_t)N * NH1;     // N
  float* al2d_ = al2s_ + N;                   // N

  // CSR build (shared by both layers)
  k_counts_init<<<(N + 255) / 256, 256, 0, stream>>>(counts, N);
  k_count<<<(E + 255) / 256, 256, 0, stream>>>(dstI, E, counts);
  k_scan<<<1, 1024, 0, stream>>>(counts, rowptr, cursor, csr, N);
  k_scatter<<<(E + 255) / 256, 256, 0, stream>>>(srcI, dstI, E, cursor, csr);

  // layer 1
  k_gemm1<<<512, 256, 0, stream>>>(x, W1, a1s, a1d, h1, al1s_, al1d_, N);
  k_aggr1<<<N, 128, 0, stream>>>(rowptr, counts, csr, al1s_, al1d_, h1, b1, out1, N);

  // layer 2 (h2 aliases h1's buffer)
  k_gemm2<<<1024, 256, 0, stream>>>(out1, W2, a2s, a2d, h1, al2s_, al2d_, N);
  k_aggr2<<<N, 64, 0, stream>>>(rowptr, counts, csr, al2s_, al2d_, h1, b2, out, N);
}

// Round 3
// 524.810 us; speedup vs baseline: 6.7634x; 3.2318x over previous
//
#include <hip/hip_runtime.h>
#include <hip/hip_bf16.h>
#include <cstdint>
#include <cstddef>

#define IN_F 128
#define HID 128
#define NH1 4
#define OUTF 64

__device__ __forceinline__ float lrelu(float v) { return v > 0.f ? v : 0.2f * v; }
__device__ __forceinline__ float eluf(float v) { return v > 0.f ? v : (__expf(v) - 1.f); }

// ---------------------------------------------------------------- CSR build
__global__ void k_counts_init(int* __restrict__ counts, int N) {
  int t = blockIdx.x * blockDim.x + threadIdx.x;
  if (t < N) counts[t] = 1;  // self-loop
}

__global__ void k_count(const int* __restrict__ dst, int E, int* __restrict__ counts) {
  int e = blockIdx.x * blockDim.x + threadIdx.x;
  if (e < E) atomicAdd(counts + dst[e], 1);
}

// single-block exclusive scan over N counts -> rowptr; also seed cursor & self-loop entry
__global__ __launch_bounds__(1024) void k_scan(const int* __restrict__ counts,
                                               int* __restrict__ rowptr,
                                               int* __restrict__ cursor,
                                               int* __restrict__ csr, int N) {
  __shared__ int sums[1024];
  const int t = threadIdx.x;
  const int chunk = (N + 1023) / 1024;
  const int lo = t * chunk, hi = min(N, lo + chunk);
  int s = 0;
  for (int i = lo; i < hi; ++i) s += counts[i];
  sums[t] = s;
  __syncthreads();
  for (int off = 1; off < 1024; off <<= 1) {
    int v = (t >= off) ? sums[t - off] : 0;
    __syncthreads();
    sums[t] += v;
    __syncthreads();
  }
  int excl = (t == 0) ? 0 : sums[t - 1];
  for (int i = lo; i < hi; ++i) {
    rowptr[i] = excl;
    cursor[i] = excl + 1;   // slot 0 reserved for self-loop
    csr[excl] = i;          // self-loop src = i
    excl += counts[i];
  }
}

__global__ void k_scatter(const int* __restrict__ src, const int* __restrict__ dst, int E,
                          int* __restrict__ cursor, int* __restrict__ csr) {
  int e = blockIdx.x * blockDim.x + threadIdx.x;
  if (e < E) {
    int d = dst[e];
    int pos = atomicAdd(cursor + d, 1);
    csr[pos] = src[e];
  }
}

// ---------------------------------------------------------------- layer-1 GEMM + attention dots
// W1 (128x128 = 64 KB) staged in LDS ONCE per block; x rows read via wave-uniform
// scalar loads; each wave processes 4 rows, lane owns cols (lane, lane+64).
__global__ __launch_bounds__(256) void k_gemm1(
    const float* __restrict__ x, const float* __restrict__ W,
    const float* __restrict__ a_s, const float* __restrict__ a_d,
    float* __restrict__ h, float* __restrict__ als, float* __restrict__ ald, int N) {
  __shared__ float Ws[IN_F * HID];  // 64 KB
  const int wave = threadIdx.x >> 6, lane = threadIdx.x & 63;
  for (int i = threadIdx.x * 4; i < IN_F * HID; i += 256 * 4)
    *(float4*)(Ws + i) = *(const float4*)(W + i);
  __syncthreads();
  const float as0 = a_s[lane], as1 = a_s[lane + 64];
  const float ad0 = a_d[lane], ad1 = a_d[lane + 64];
  const int stride = gridDim.x * 16;
  for (int base = blockIdx.x * 16 + wave * 4; base < N; base += stride) {
    const int r0 = __builtin_amdgcn_readfirstlane(base);
    const float* __restrict__ xr = x + (size_t)r0 * IN_F;
    float acc[4][2] = {{0.f,0.f},{0.f,0.f},{0.f,0.f},{0.f,0.f}};
    if (r0 + 4 <= N) {
      for (int k = 0; k < IN_F; k += 4) {
        float4 xq[4];
        #pragma unroll
        for (int ri = 0; ri < 4; ++ri) xq[ri] = *(const float4*)(xr + ri * IN_F + k);
        #pragma unroll
        for (int kk = 0; kk < 4; ++kk) {
          const float w0 = Ws[(k + kk) * HID + lane];
          const float w1 = Ws[(k + kk) * HID + lane + 64];
          #pragma unroll
          for (int ri = 0; ri < 4; ++ri) {
            const float xv = ((const float*)&xq[ri])[kk];
            acc[ri][0] += xv * w0;
            acc[ri][1] += xv * w1;
          }
        }
      }
    } else {
      const int vr = N - r0;
      for (int k = 0; k < IN_F; ++k) {
        const float w0 = Ws[k * HID + lane];
        const float w1 = Ws[k * HID + lane + 64];
        for (int ri = 0; ri < vr; ++ri) {
          const float xv = xr[ri * IN_F + k];
          acc[ri][0] += xv * w0;
          acc[ri][1] += xv * w1;
        }
      }
    }
    const int vr = min(4, N - r0);
    #pragma unroll
    for (int ri = 0; ri < 4; ++ri) {
      if (ri < vr) {
        const int r = r0 + ri;
        h[(size_t)r * HID + lane]      = acc[ri][0];
        h[(size_t)r * HID + lane + 64] = acc[ri][1];
      }
    }
    #pragma unroll
    for (int ri = 0; ri < 4; ++ri) {
      float ps0 = acc[ri][0] * as0, pd0 = acc[ri][0] * ad0;
      float ps1 = acc[ri][1] * as1, pd1 = acc[ri][1] * ad1;
      #pragma unroll
      for (int m = 16; m >= 1; m >>= 1) {
        ps0 += __shfl_xor(ps0, m, 32); pd0 += __shfl_xor(pd0, m, 32);
        ps1 += __shfl_xor(ps1, m, 32); pd1 += __shfl_xor(pd1, m, 32);
      }
      if (ri < vr && (lane & 31) == 0) {
        const int r = r0 + ri, hh = lane >> 5;
        als[r * NH1 + hh]     = ps0;  ald[r * NH1 + hh]     = pd0;
        als[r * NH1 + 2 + hh] = ps1;  ald[r * NH1 + 2 + hh] = pd1;
      }
    }
  }
}

// ---------------------------------------------------------------- layer-2 GEMM
// input rows already ELU'd (fused into k_aggr1). W2 (128x64 = 32 KB) in LDS once.
__global__ __launch_bounds__(256) void k_gemm2(
    const float* __restrict__ hin, const float* __restrict__ W,
    const float* __restrict__ a_s, const float* __restrict__ a_d,
    float* __restrict__ h, float* __restrict__ als, float* __restrict__ ald, int N) {
  __shared__ float Ws[HID * OUTF];  // 32 KB
  const int wave = threadIdx.x >> 6, lane = threadIdx.x & 63;
  for (int i = threadIdx.x * 4; i < HID * OUTF; i += 256 * 4)
    *(float4*)(Ws + i) = *(const float4*)(W + i);
  __syncthreads();
  const float asj = a_s[lane], adj = a_d[lane];
  const int stride = gridDim.x * 16;
  for (int base = blockIdx.x * 16 + wave * 4; base < N; base += stride) {
    const int r0 = __builtin_amdgcn_readfirstlane(base);
    const float* __restrict__ xr = hin + (size_t)r0 * HID;
    float acc[4] = {0.f, 0.f, 0.f, 0.f};
    if (r0 + 4 <= N) {
      for (int k = 0; k < HID; k += 4) {
        float4 xq[4];
        #pragma unroll
        for (int ri = 0; ri < 4; ++ri) xq[ri] = *(const float4*)(xr + ri * HID + k);
        #pragma unroll
        for (int kk = 0; kk < 4; ++kk) {
          const float w0 = Ws[(k + kk) * OUTF + lane];
          #pragma unroll
          for (int ri = 0; ri < 4; ++ri) acc[ri] += ((const float*)&xq[ri])[kk] * w0;
        }
      }
    } else {
      const int vr = N - r0;
      for (int k = 0; k < HID; ++k) {
        const float w0 = Ws[k * OUTF + lane];
        for (int ri = 0; ri < vr; ++ri) acc[ri] += xr[ri * HID + k] * w0;
      }
    }
    const int vr = min(4, N - r0);
    #pragma unroll
    for (int ri = 0; ri < 4; ++ri) {
      if (ri < vr) h[(size_t)(r0 + ri) * OUTF + lane] = acc[ri];
    }
    #pragma unroll
    for (int ri = 0; ri < 4; ++ri) {
      float ps = acc[ri] * asj, pd = acc[ri] * adj;
      #pragma unroll
      for (int m = 32; m >= 1; m >>= 1) {
        ps += __shfl_xor(ps, m, 64); pd += __shfl_xor(pd, m, 64);
      }
      if (ri < vr && lane == 0) { als[r0 + ri] = ps; ald[r0 + ri] = pd; }
    }
  }
}

// ---------------------------------------------------------------- gather softmax+aggregation, layer 1
// one block (128 thr) per dst node; lane j owns feature j; head = j>>5.
// Single-pass online softmax; ELU + bias fused into epilogue.
__global__ __launch_bounds__(128) void k_aggr1(
    const int* __restrict__ rowptr, const int* __restrict__ counts,
    const int* __restrict__ csr,
    const float* __restrict__ als, const float* __restrict__ ald,
    const float* __restrict__ h, const float* __restrict__ b,
    float* __restrict__ out, int N) {
  const int d = blockIdx.x;
  if (d >= N) return;
  const int j = threadIdx.x;
  const int head = j >> 5;
  const int row0 = rowptr[d];
  const int deg = counts[d];
  const float aldh = ald[d * NH1 + head];
  float m = -1e30f, sum = 0.f, acc = 0.f;
  for (int i = 0; i < deg; ++i) {
    const int s = csr[row0 + i];
    const float v = lrelu(als[s * NH1 + head] + aldh);
    const float hv = h[(size_t)s * HID + j];
    if (v > m) { const float sc = __expf(m - v); sum *= sc; acc *= sc; m = v; }
    const float p = __expf(v - m);
    sum += p;
    acc += p * hv;
  }
  out[(size_t)d * HID + j] = eluf(acc / (sum + 1e-16f) + b[j]);
}

// ---------------------------------------------------------------- gather softmax+aggregation, layer 2
__global__ __launch_bounds__(64) void k_aggr2(
    const int* __restrict__ rowptr, const int* __restrict__ counts,
    const int* __restrict__ csr,
    const float* __restrict__ als, const float* __restrict__ ald,
    const float* __restrict__ h, const float* __restrict__ b,
    float* __restrict__ out, int N) {
  const int d = blockIdx.x;
  if (d >= N) return;
  const int j = threadIdx.x;
  const int row0 = rowptr[d];
  const int deg = counts[d];
  const float aldd = ald[d];
  float m = -1e30f, sum = 0.f, acc = 0.f;
  for (int i = 0; i < deg; ++i) {
    const int s = csr[row0 + i];
    const float v = lrelu(als[s] + aldd);
    const float hv = h[(size_t)s * OUTF + j];
    if (v > m) { const float sc = __expf(m - v); sum *= sc; acc *= sc; m = v; }
    const float p = __expf(v - m);
    sum += p;
    acc += p * hv;
  }
  out[(size_t)d * OUTF + j] = acc / (sum + 1e-16f) + b[j];
}

// ---------------------------------------------------------------- launch
extern "C" void kernel_launch(void* const* d_in, const int* in_sizes, int n_in,
                              void* d_out, int out_size, void* d_ws, size_t ws_size,
                              hipStream_t stream) {
  const float* x   = (const float*)d_in[0];
  const int*   ei  = (const int*)d_in[1];
  const float* W1  = (const float*)d_in[2];
  const float* a1s = (const float*)d_in[3];
  const float* a1d = (const float*)d_in[4];
  const float* b1  = (const float*)d_in[5];
  const float* W2  = (const float*)d_in[6];
  const float* a2s = (const float*)d_in[7];
  const float* a2d = (const float*)d_in[8];
  const float* b2  = (const float*)d_in[9];
  float* out = (float*)d_out;

  const int N = in_sizes[0] / IN_F;
  const int E = in_sizes[1] / 2;
  const int* srcI = ei;
  const int* dstI = ei + E;

  // workspace layout (ints first, then 16B-aligned floats)
  int* rowptr = (int*)d_ws;                   // N
  int* counts = rowptr + N;                   // N
  int* cursor = counts + N;                   // N
  int* csr    = cursor + N;                   // E+N
  size_t int_end = (size_t)(3 * N + E + N);
  int_end = (int_end + 3) & ~(size_t)3;       // 16B alignment for float4
  float* h1    = (float*)d_ws + int_end;      // N*128 (reused as h2: N*64)
  float* out1  = h1 + (size_t)N * HID;        // N*128 (post-ELU)
  float* al1s_ = out1 + (size_t)N * HID;      // N*4
  float* al1d_ = al1s_ + (size_t)N * NH1;     // N*4
  float* al2s_ = al1d_ + (size_t)N * NH1;     // N
  float* al2d_ = al2s_ + N;                   // N

  // CSR build (shared by both layers)
  k_counts_init<<<(N + 255) / 256, 256, 0, stream>>>(counts, N);
  k_count<<<(E + 255) / 256, 256, 0, stream>>>(dstI, E, counts);
  k_scan<<<1, 1024, 0, stream>>>(counts, rowptr, cursor, csr, N);
  k_scatter<<<(E + 255) / 256, 256, 0, stream>>>(srcI, dstI, E, cursor, csr);

  // layer 1
  k_gemm1<<<512, 256, 0, stream>>>(x, W1, a1s, a1d, h1, al1s_, al1d_, N);
  k_aggr1<<<N, 128, 0, stream>>>(rowptr, counts, csr, al1s_, al1d_, h1, b1, out1, N);

  // layer 2 (h2 aliases h1's buffer)
  k_gemm2<<<512, 256, 0, stream>>>(out1, W2, a2s, a2d, h1, al2s_, al2d_, N);
  k_aggr2<<<N, 64, 0, stream>>>(rowptr, counts, csr, al2s_, al2d_, h1, b2, out, N);
}

// Round 4
// 397.069 us; speedup vs baseline: 8.9392x; 1.3217x over previous
//
#include <hip/hip_runtime.h>
#include <hip/hip_bf16.h>
#include <cstdint>
#include <cstddef>

#define IN_F 128
#define HID 128
#define NH1 4
#define OUTF 64

__device__ __forceinline__ float lrelu(float v) { return v > 0.f ? v : 0.2f * v; }
__device__ __forceinline__ float eluf(float v) { return v > 0.f ? v : (__expf(v) - 1.f); }

// ---------------------------------------------------------------- CSR build
__global__ void k_counts_init(int* __restrict__ counts, int N) {
  int t = blockIdx.x * blockDim.x + threadIdx.x;
  if (t < N) counts[t] = 1;  // self-loop
}

__global__ void k_count(const int* __restrict__ dst, int E, int* __restrict__ counts) {
  int e = blockIdx.x * blockDim.x + threadIdx.x;
  if (e < E) atomicAdd(counts + dst[e], 1);
}

// hierarchical scan, phase A: per-block reduction of 256 counts
__global__ __launch_bounds__(256) void k_scan_a(const int* __restrict__ counts,
                                                int* __restrict__ partial, int N) {
  __shared__ int red[256];
  const int i = blockIdx.x * 256 + threadIdx.x;
  red[threadIdx.x] = (i < N) ? counts[i] : 0;
  __syncthreads();
  #pragma unroll
  for (int off = 128; off > 0; off >>= 1) {
    if (threadIdx.x < off) red[threadIdx.x] += red[threadIdx.x + off];
    __syncthreads();
  }
  if (threadIdx.x == 0) partial[blockIdx.x] = red[0];
}

// phase B: single small block scans the <=1024 block partials (exclusive, in place)
__global__ __launch_bounds__(1024) void k_scan_b(int* __restrict__ partial, int nb) {
  __shared__ int sm[1024];
  const int t = threadIdx.x;
  const int v = (t < nb) ? partial[t] : 0;
  sm[t] = v;
  __syncthreads();
  #pragma unroll
  for (int off = 1; off < 1024; off <<= 1) {
    const int u = (t >= off) ? sm[t - off] : 0;
    __syncthreads();
    sm[t] += u;
    __syncthreads();
  }
  if (t < nb) partial[t] = sm[t] - v;  // exclusive
}

// phase C: per-block exclusive scan + global offset; emit rowptr/cursor/self-loop
__global__ __launch_bounds__(256) void k_scan_c(const int* __restrict__ counts,
                                                const int* __restrict__ partial,
                                                int* __restrict__ rowptr,
                                                int* __restrict__ cursor,
                                                int* __restrict__ csr, int N) {
  __shared__ int sm[256];
  const int i = blockIdx.x * 256 + threadIdx.x;
  const int t = threadIdx.x;
  const int v = (i < N) ? counts[i] : 0;
  sm[t] = v;
  __syncthreads();
  #pragma unroll
  for (int off = 1; off < 256; off <<= 1) {
    const int u = (t >= off) ? sm[t - off] : 0;
    __syncthreads();
    sm[t] += u;
    __syncthreads();
  }
  if (i < N) {
    const int e = partial[blockIdx.x] + sm[t] - v;
    rowptr[i] = e;
    cursor[i] = e + 1;   // slot 0 reserved for self-loop
    csr[e] = i;          // self-loop src = i
  }
}

__global__ void k_scatter(const int* __restrict__ src, const int* __restrict__ dst, int E,
                          int* __restrict__ cursor, int* __restrict__ csr) {
  int e = blockIdx.x * blockDim.x + threadIdx.x;
  if (e < E) {
    int d = dst[e];
    int pos = atomicAdd(cursor + d, 1);
    csr[pos] = src[e];
  }
}

// ---------------------------------------------------------------- layer-1 GEMM + attention dots
// W1 (128x128 = 64 KB) staged in LDS ONCE per block; x rows read via wave-uniform
// scalar loads; each wave processes 4 rows, lane owns cols (lane, lane+64).
__global__ __launch_bounds__(256) void k_gemm1(
    const float* __restrict__ x, const float* __restrict__ W,
    const float* __restrict__ a_s, const float* __restrict__ a_d,
    float* __restrict__ h, float* __restrict__ als, float* __restrict__ ald, int N) {
  __shared__ float Ws[IN_F * HID];  // 64 KB
  const int wave = threadIdx.x >> 6, lane = threadIdx.x & 63;
  for (int i = threadIdx.x * 4; i < IN_F * HID; i += 256 * 4)
    *(float4*)(Ws + i) = *(const float4*)(W + i);
  __syncthreads();
  const float as0 = a_s[lane], as1 = a_s[lane + 64];
  const float ad0 = a_d[lane], ad1 = a_d[lane + 64];
  const int stride = gridDim.x * 16;
  for (int base = blockIdx.x * 16 + wave * 4; base < N; base += stride) {
    const int r0 = __builtin_amdgcn_readfirstlane(base);
    const float* __restrict__ xr = x + (size_t)r0 * IN_F;
    float acc[4][2] = {{0.f,0.f},{0.f,0.f},{0.f,0.f},{0.f,0.f}};
    if (r0 + 4 <= N) {
      for (int k = 0; k < IN_F; k += 4) {
        float4 xq[4];
        #pragma unroll
        for (int ri = 0; ri < 4; ++ri) xq[ri] = *(const float4*)(xr + ri * IN_F + k);
        #pragma unroll
        for (int kk = 0; kk < 4; ++kk) {
          const float w0 = Ws[(k + kk) * HID + lane];
          const float w1 = Ws[(k + kk) * HID + lane + 64];
          #pragma unroll
          for (int ri = 0; ri < 4; ++ri) {
            const float xv = ((const float*)&xq[ri])[kk];
            acc[ri][0] += xv * w0;
            acc[ri][1] += xv * w1;
          }
        }
      }
    } else {
      const int vr = N - r0;
      for (int k = 0; k < IN_F; ++k) {
        const float w0 = Ws[k * HID + lane];
        const float w1 = Ws[k * HID + lane + 64];
        for (int ri = 0; ri < vr; ++ri) {
          const float xv = xr[ri * IN_F + k];
          acc[ri][0] += xv * w0;
          acc[ri][1] += xv * w1;
        }
      }
    }
    const int vr = min(4, N - r0);
    #pragma unroll
    for (int ri = 0; ri < 4; ++ri) {
      if (ri < vr) {
        const int r = r0 + ri;
        h[(size_t)r * HID + lane]      = acc[ri][0];
        h[(size_t)r * HID + lane + 64] = acc[ri][1];
      }
    }
    #pragma unroll
    for (int ri = 0; ri < 4; ++ri) {
      float ps0 = acc[ri][0] * as0, pd0 = acc[ri][0] * ad0;
      float ps1 = acc[ri][1] * as1, pd1 = acc[ri][1] * ad1;
      #pragma unroll
      for (int m = 16; m >= 1; m >>= 1) {
        ps0 += __shfl_xor(ps0, m, 32); pd0 += __shfl_xor(pd0, m, 32);
        ps1 += __shfl_xor(ps1, m, 32); pd1 += __shfl_xor(pd1, m, 32);
      }
      if (ri < vr && (lane & 31) == 0) {
        const int r = r0 + ri, hh = lane >> 5;
        als[r * NH1 + hh]     = ps0;  ald[r * NH1 + hh]     = pd0;
        als[r * NH1 + 2 + hh] = ps1;  ald[r * NH1 + 2 + hh] = pd1;
      }
    }
  }
}

// ---------------------------------------------------------------- layer-2 GEMM
// input rows already ELU'd (fused into k_aggr1). W2 (128x64 = 32 KB) in LDS once.
__global__ __launch_bounds__(256) void k_gemm2(
    const float* __restrict__ hin, const float* __restrict__ W,
    const float* __restrict__ a_s, const float* __restrict__ a_d,
    float* __restrict__ h, float* __restrict__ als, float* __restrict__ ald, int N) {
  __shared__ float Ws[HID * OUTF];  // 32 KB
  const int wave = threadIdx.x >> 6, lane = threadIdx.x & 63;
  for (int i = threadIdx.x * 4; i < HID * OUTF; i += 256 * 4)
    *(float4*)(Ws + i) = *(const float4*)(W + i);
  __syncthreads();
  const float asj = a_s[lane], adj = a_d[lane];
  const int stride = gridDim.x * 16;
  for (int base = blockIdx.x * 16 + wave * 4; base < N; base += stride) {
    const int r0 = __builtin_amdgcn_readfirstlane(base);
    const float* __restrict__ xr = hin + (size_t)r0 * HID;
    float acc[4] = {0.f, 0.f, 0.f, 0.f};
    if (r0 + 4 <= N) {
      for (int k = 0; k < HID; k += 4) {
        float4 xq[4];
        #pragma unroll
        for (int ri = 0; ri < 4; ++ri) xq[ri] = *(const float4*)(xr + ri * HID + k);
        #pragma unroll
        for (int kk = 0; kk < 4; ++kk) {
          const float w0 = Ws[(k + kk) * OUTF + lane];
          #pragma unroll
          for (int ri = 0; ri < 4; ++ri) acc[ri] += ((const float*)&xq[ri])[kk] * w0;
        }
      }
    } else {
      const int vr = N - r0;
      for (int k = 0; k < HID; ++k) {
        const float w0 = Ws[k * OUTF + lane];
        for (int ri = 0; ri < vr; ++ri) acc[ri] += xr[ri * HID + k] * w0;
      }
    }
    const int vr = min(4, N - r0);
    #pragma unroll
    for (int ri = 0; ri < 4; ++ri) {
      if (ri < vr) h[(size_t)(r0 + ri) * OUTF + lane] = acc[ri];
    }
    #pragma unroll
    for (int ri = 0; ri < 4; ++ri) {
      float ps = acc[ri] * asj, pd = acc[ri] * adj;
      #pragma unroll
      for (int m = 32; m >= 1; m >>= 1) {
        ps += __shfl_xor(ps, m, 64); pd += __shfl_xor(pd, m, 64);
      }
      if (ri < vr && lane == 0) { als[r0 + ri] = ps; ald[r0 + ri] = pd; }
    }
  }
}

// ---------------------------------------------------------------- gather softmax+aggregation, layer 1
// one block (128 thr) per dst node; lane j owns feature j; head = j>>5.
// Single-pass online softmax; ELU + bias fused into epilogue.
__global__ __launch_bounds__(128) void k_aggr1(
    const int* __restrict__ rowptr, const int* __restrict__ counts,
    const int* __restrict__ csr,
    const float* __restrict__ als, const float* __restrict__ ald,
    const float* __restrict__ h, const float* __restrict__ b,
    float* __restrict__ out, int N) {
  const int d = blockIdx.x;
  if (d >= N) return;
  const int j = threadIdx.x;
  const int head = j >> 5;
  const int row0 = rowptr[d];
  const int deg = counts[d];
  const float aldh = ald[d * NH1 + head];
  float m = -1e30f, sum = 0.f, acc = 0.f;
  for (int i = 0; i < deg; ++i) {
    const int s = csr[row0 + i];
    const float v = lrelu(als[s * NH1 + head] + aldh);
    const float hv = h[(size_t)s * HID + j];
    if (v > m) { const float sc = __expf(m - v); sum *= sc; acc *= sc; m = v; }
    const float p = __expf(v - m);
    sum += p;
    acc += p * hv;
  }
  out[(size_t)d * HID + j] = eluf(acc / (sum + 1e-16f) + b[j]);
}

// ---------------------------------------------------------------- gather softmax+aggregation, layer 2
__global__ __launch_bounds__(64) void k_aggr2(
    const int* __restrict__ rowptr, const int* __restrict__ counts,
    const int* __restrict__ csr,
    const float* __restrict__ als, const float* __restrict__ ald,
    const float* __restrict__ h, const float* __restrict__ b,
    float* __restrict__ out, int N) {
  const int d = blockIdx.x;
  if (d >= N) return;
  const int j = threadIdx.x;
  const int row0 = rowptr[d];
  const int deg = counts[d];
  const float aldd = ald[d];
  float m = -1e30f, sum = 0.f, acc = 0.f;
  for (int i = 0; i < deg; ++i) {
    const int s = csr[row0 + i];
    const float v = lrelu(als[s] + aldd);
    const float hv = h[(size_t)s * OUTF + j];
    if (v > m) { const float sc = __expf(m - v); sum *= sc; acc *= sc; m = v; }
    const float p = __expf(v - m);
    sum += p;
    acc += p * hv;
  }
  out[(size_t)d * OUTF + j] = acc / (sum + 1e-16f) + b[j];
}

// ---------------------------------------------------------------- launch
extern "C" void kernel_launch(void* const* d_in, const int* in_sizes, int n_in,
                              void* d_out, int out_size, void* d_ws, size_t ws_size,
                              hipStream_t stream) {
  const float* x   = (const float*)d_in[0];
  const int*   ei  = (const int*)d_in[1];
  const float* W1  = (const float*)d_in[2];
  const float* a1s = (const float*)d_in[3];
  const float* a1d = (const float*)d_in[4];
  const float* b1  = (const float*)d_in[5];
  const float* W2  = (const float*)d_in[6];
  const float* a2s = (const float*)d_in[7];
  const float* a2d = (const float*)d_in[8];
  const float* b2  = (const float*)d_in[9];
  float* out = (float*)d_out;

  const int N = in_sizes[0] / IN_F;
  const int E = in_sizes[1] / 2;
  const int* srcI = ei;
  const int* dstI = ei + E;
  const int nb = (N + 255) / 256;   // scan blocks (<=1024 supported by k_scan_b)

  // workspace layout (ints first, then 16B-aligned floats)
  int* rowptr  = (int*)d_ws;                  // N
  int* counts  = rowptr + N;                  // N
  int* cursor  = counts + N;                  // N
  int* partial = cursor + N;                  // nb (<=1024)
  int* csr     = partial + 1024;              // E+N
  size_t int_end = (size_t)(3 * N + 1024 + E + N);
  int_end = (int_end + 3) & ~(size_t)3;       // 16B alignment for float4
  float* h1    = (float*)d_ws + int_end;      // N*128 (reused as h2: N*64)
  float* out1  = h1 + (size_t)N * HID;        // N*128 (post-ELU)
  float* al1s_ = out1 + (size_t)N * HID;      // N*4
  float* al1d_ = al1s_ + (size_t)N * NH1;     // N*4
  float* al2s_ = al1d_ + (size_t)N * NH1;     // N
  float* al2d_ = al2s_ + N;                   // N

  // CSR build (shared by both layers)
  k_counts_init<<<nb, 256, 0, stream>>>(counts, N);
  k_count<<<(E + 255) / 256, 256, 0, stream>>>(dstI, E, counts);
  k_scan_a<<<nb, 256, 0, stream>>>(counts, partial, N);
  k_scan_b<<<1, 1024, 0, stream>>>(partial, nb);
  k_scan_c<<<nb, 256, 0, stream>>>(counts, partial, rowptr, cursor, csr, N);
  k_scatter<<<(E + 255) / 256, 256, 0, stream>>>(srcI, dstI, E, cursor, csr);

  // layer 1
  k_gemm1<<<512, 256, 0, stream>>>(x, W1, a1s, a1d, h1, al1s_, al1d_, N);
  k_aggr1<<<N, 128, 0, stream>>>(rowptr, counts, csr, al1s_, al1d_, h1, b1, out1, N);

  // layer 2 (h2 aliases h1's buffer)
  k_gemm2<<<512, 256, 0, stream>>>(out1, W2, a2s, a2d, h1, al2s_, al2d_, N);
  k_aggr2<<<N, 64, 0, stream>>>(rowptr, counts, csr, al2s_, al2d_, h1, b2, out, N);
}

// Round 5
// 366.927 us; speedup vs baseline: 9.6735x; 1.0821x over previous
//
#include <hip/hip_runtime.h>
#include <hip/hip_bf16.h>
#include <cstdint>
#include <cstddef>

#define IN_F 128
#define HID 128
#define NH1 4
#define OUTF 64

__device__ __forceinline__ float lrelu(float v) { return v > 0.f ? v : 0.2f * v; }
__device__ __forceinline__ float eluf(float v) { return v > 0.f ? v : (__expf(v) - 1.f); }

// ---------------------------------------------------------------- CSR build
__global__ void k_counts_init(int* __restrict__ counts, int N) {
  int t = blockIdx.x * blockDim.x + threadIdx.x;
  if (t < N) counts[t] = 1;  // self-loop
}

__global__ void k_count(const int* __restrict__ dst, int E, int* __restrict__ counts) {
  int e = blockIdx.x * blockDim.x + threadIdx.x;
  if (e < E) atomicAdd(counts + dst[e], 1);
}

// hierarchical scan, phase A: per-block reduction of 256 counts
__global__ __launch_bounds__(256) void k_scan_a(const int* __restrict__ counts,
                                                int* __restrict__ partial, int N) {
  __shared__ int red[256];
  const int i = blockIdx.x * 256 + threadIdx.x;
  red[threadIdx.x] = (i < N) ? counts[i] : 0;
  __syncthreads();
  #pragma unroll
  for (int off = 128; off > 0; off >>= 1) {
    if (threadIdx.x < off) red[threadIdx.x] += red[threadIdx.x + off];
    __syncthreads();
  }
  if (threadIdx.x == 0) partial[blockIdx.x] = red[0];
}

// phase B: single small block scans the <=1024 block partials (exclusive, in place)
__global__ __launch_bounds__(1024) void k_scan_b(int* __restrict__ partial, int nb) {
  __shared__ int sm[1024];
  const int t = threadIdx.x;
  const int v = (t < nb) ? partial[t] : 0;
  sm[t] = v;
  __syncthreads();
  #pragma unroll
  for (int off = 1; off < 1024; off <<= 1) {
    const int u = (t >= off) ? sm[t - off] : 0;
    __syncthreads();
    sm[t] += u;
    __syncthreads();
  }
  if (t < nb) partial[t] = sm[t] - v;  // exclusive
}

// phase C: per-block exclusive scan + global offset; emit rowptr/cursor/self-loop
__global__ __launch_bounds__(256) void k_scan_c(const int* __restrict__ counts,
                                                const int* __restrict__ partial,
                                                int* __restrict__ rowptr,
                                                int* __restrict__ cursor,
                                                int* __restrict__ csr, int N) {
  __shared__ int sm[256];
  const int i = blockIdx.x * 256 + threadIdx.x;
  const int t = threadIdx.x;
  const int v = (i < N) ? counts[i] : 0;
  sm[t] = v;
  __syncthreads();
  #pragma unroll
  for (int off = 1; off < 256; off <<= 1) {
    const int u = (t >= off) ? sm[t - off] : 0;
    __syncthreads();
    sm[t] += u;
    __syncthreads();
  }
  if (i < N) {
    const int e = partial[blockIdx.x] + sm[t] - v;
    rowptr[i] = e;
    cursor[i] = e + 1;   // slot 0 reserved for self-loop
    csr[e] = i;          // self-loop src = i
  }
}

__global__ void k_scatter(const int* __restrict__ src, const int* __restrict__ dst, int E,
                          int* __restrict__ cursor, int* __restrict__ csr) {
  int e = blockIdx.x * blockDim.x + threadIdx.x;
  if (e < E) {
    int d = dst[e];
    int pos = atomicAdd(cursor + d, 1);
    csr[pos] = src[e];
  }
}

// ---------------------------------------------------------------- layer-1 GEMM + attention dots
__global__ __launch_bounds__(256) void k_gemm1(
    const float* __restrict__ x, const float* __restrict__ W,
    const float* __restrict__ a_s, const float* __restrict__ a_d,
    float* __restrict__ h, float* __restrict__ als, float* __restrict__ ald, int N) {
  __shared__ float Ws[IN_F * HID];  // 64 KB
  const int wave = threadIdx.x >> 6, lane = threadIdx.x & 63;
  for (int i = threadIdx.x * 4; i < IN_F * HID; i += 256 * 4)
    *(float4*)(Ws + i) = *(const float4*)(W + i);
  __syncthreads();
  const float as0 = a_s[lane], as1 = a_s[lane + 64];
  const float ad0 = a_d[lane], ad1 = a_d[lane + 64];
  const int stride = gridDim.x * 16;
  for (int base = blockIdx.x * 16 + wave * 4; base < N; base += stride) {
    const int r0 = __builtin_amdgcn_readfirstlane(base);
    const float* __restrict__ xr = x + (size_t)r0 * IN_F;
    float acc[4][2] = {{0.f,0.f},{0.f,0.f},{0.f,0.f},{0.f,0.f}};
    if (r0 + 4 <= N) {
      for (int k = 0; k < IN_F; k += 4) {
        float4 xq[4];
        #pragma unroll
        for (int ri = 0; ri < 4; ++ri) xq[ri] = *(const float4*)(xr + ri * IN_F + k);
        #pragma unroll
        for (int kk = 0; kk < 4; ++kk) {
          const float w0 = Ws[(k + kk) * HID + lane];
          const float w1 = Ws[(k + kk) * HID + lane + 64];
          #pragma unroll
          for (int ri = 0; ri < 4; ++ri) {
            const float xv = ((const float*)&xq[ri])[kk];
            acc[ri][0] += xv * w0;
            acc[ri][1] += xv * w1;
          }
        }
      }
    } else {
      const int vr = N - r0;
      for (int k = 0; k < IN_F; ++k) {
        const float w0 = Ws[k * HID + lane];
        const float w1 = Ws[k * HID + lane + 64];
        for (int ri = 0; ri < vr; ++ri) {
          const float xv = xr[ri * IN_F + k];
          acc[ri][0] += xv * w0;
          acc[ri][1] += xv * w1;
        }
      }
    }
    const int vr = min(4, N - r0);
    #pragma unroll
    for (int ri = 0; ri < 4; ++ri) {
      if (ri < vr) {
        const int r = r0 + ri;
        h[(size_t)r * HID + lane]      = acc[ri][0];
        h[(size_t)r * HID + lane + 64] = acc[ri][1];
      }
    }
    #pragma unroll
    for (int ri = 0; ri < 4; ++ri) {
      float ps0 = acc[ri][0] * as0, pd0 = acc[ri][0] * ad0;
      float ps1 = acc[ri][1] * as1, pd1 = acc[ri][1] * ad1;
      #pragma unroll
      for (int m = 16; m >= 1; m >>= 1) {
        ps0 += __shfl_xor(ps0, m, 32); pd0 += __shfl_xor(pd0, m, 32);
        ps1 += __shfl_xor(ps1, m, 32); pd1 += __shfl_xor(pd1, m, 32);
      }
      if (ri < vr && (lane & 31) == 0) {
        const int r = r0 + ri, hh = lane >> 5;
        als[r * NH1 + hh]     = ps0;  ald[r * NH1 + hh]     = pd0;
        als[r * NH1 + 2 + hh] = ps1;  ald[r * NH1 + 2 + hh] = pd1;
      }
    }
  }
}

// ---------------------------------------------------------------- layer-2 GEMM
__global__ __launch_bounds__(256) void k_gemm2(
    const float* __restrict__ hin, const float* __restrict__ W,
    const float* __restrict__ a_s, const float* __restrict__ a_d,
    float* __restrict__ h, float* __restrict__ als, float* __restrict__ ald, int N) {
  __shared__ float Ws[HID * OUTF];  // 32 KB
  const int wave = threadIdx.x >> 6, lane = threadIdx.x & 63;
  for (int i = threadIdx.x * 4; i < HID * OUTF; i += 256 * 4)
    *(float4*)(Ws + i) = *(const float4*)(W + i);
  __syncthreads();
  const float asj = a_s[lane], adj = a_d[lane];
  const int stride = gridDim.x * 16;
  for (int base = blockIdx.x * 16 + wave * 4; base < N; base += stride) {
    const int r0 = __builtin_amdgcn_readfirstlane(base);
    const float* __restrict__ xr = hin + (size_t)r0 * HID;
    float acc[4] = {0.f, 0.f, 0.f, 0.f};
    if (r0 + 4 <= N) {
      for (int k = 0; k < HID; k += 4) {
        float4 xq[4];
        #pragma unroll
        for (int ri = 0; ri < 4; ++ri) xq[ri] = *(const float4*)(xr + ri * HID + k);
        #pragma unroll
        for (int kk = 0; kk < 4; ++kk) {
          const float w0 = Ws[(k + kk) * OUTF + lane];
          #pragma unroll
          for (int ri = 0; ri < 4; ++ri) acc[ri] += ((const float*)&xq[ri])[kk] * w0;
        }
      }
    } else {
      const int vr = N - r0;
      for (int k = 0; k < HID; ++k) {
        const float w0 = Ws[k * OUTF + lane];
        for (int ri = 0; ri < vr; ++ri) acc[ri] += xr[ri * HID + k] * w0;
      }
    }
    const int vr = min(4, N - r0);
    #pragma unroll
    for (int ri = 0; ri < 4; ++ri) {
      if (ri < vr) h[(size_t)(r0 + ri) * OUTF + lane] = acc[ri];
    }
    #pragma unroll
    for (int ri = 0; ri < 4; ++ri) {
      float ps = acc[ri] * asj, pd = acc[ri] * adj;
      #pragma unroll
      for (int m = 32; m >= 1; m >>= 1) {
        ps += __shfl_xor(ps, m, 64); pd += __shfl_xor(pd, m, 64);
      }
      if (ri < vr && lane == 0) { als[r0 + ri] = ps; ald[r0 + ri] = pd; }
    }
  }
}

// ---------------------------------------------------------------- attention softmax, layer 1
// one wave per dst node; lane = slot*4+head (16 edge-slots x 4 heads).
// writes unnormalized p=exp(v-m) per CSR slot and rinv=1/(sum+eps) per (d,head).
__global__ __launch_bounds__(64) void k_att1(
    const int* __restrict__ rowptr, const int* __restrict__ counts,
    const int* __restrict__ csr,
    const float* __restrict__ als, const float* __restrict__ ald,
    float* __restrict__ praw, float* __restrict__ rinv, int N) {
  const int d = blockIdx.x;
  if (d >= N) return;
  const int lane = threadIdx.x;
  const int slot = lane >> 2, head = lane & 3;
  const int row0 = rowptr[d], deg = counts[d];
  const float aldh = ald[d * NH1 + head];
  float vmax = -1e30f;
  for (int i = slot; i < deg; i += 16) {
    const int s = csr[row0 + i];
    vmax = fmaxf(vmax, lrelu(als[s * NH1 + head] + aldh));
  }
  #pragma unroll
  for (int mk = 4; mk <= 32; mk <<= 1) vmax = fmaxf(vmax, __shfl_xor(vmax, mk, 64));
  float sum = 0.f;
  for (int i = slot; i < deg; i += 16) {
    const int s = csr[row0 + i];
    const float v = lrelu(als[s * NH1 + head] + aldh);
    const float p = __expf(v - vmax);
    sum += p;
    praw[(size_t)(row0 + i) * NH1 + head] = p;
  }
  #pragma unroll
  for (int mk = 4; mk <= 32; mk <<= 1) sum += __shfl_xor(sum, mk, 64);
  if (slot == 0) rinv[d * NH1 + head] = 1.f / (sum + 1e-16f);
}

// ---------------------------------------------------------------- attention softmax, layer 2 (H=1)
__global__ __launch_bounds__(64) void k_att2(
    const int* __restrict__ rowptr, const int* __restrict__ counts,
    const int* __restrict__ csr,
    const float* __restrict__ als, const float* __restrict__ ald,
    float* __restrict__ praw, float* __restrict__ rinv, int N) {
  const int d = blockIdx.x;
  if (d >= N) return;
  const int lane = threadIdx.x;
  const int row0 = rowptr[d], deg = counts[d];
  const float aldd = ald[d];
  float vmax = -1e30f;
  for (int i = lane; i < deg; i += 64) {
    const int s = csr[row0 + i];
    vmax = fmaxf(vmax, lrelu(als[s] + aldd));
  }
  #pragma unroll
  for (int mk = 1; mk <= 32; mk <<= 1) vmax = fmaxf(vmax, __shfl_xor(vmax, mk, 64));
  float sum = 0.f;
  for (int i = lane; i < deg; i += 64) {
    const int s = csr[row0 + i];
    const float p = __expf(lrelu(als[s] + aldd) - vmax);
    sum += p;
    praw[row0 + i] = p;
  }
  #pragma unroll
  for (int mk = 1; mk <= 32; mk <<= 1) sum += __shfl_xor(sum, mk, 64);
  if (lane == 0) rinv[d] = 1.f / (sum + 1e-16f);
}

// ---------------------------------------------------------------- weighted gather, layer 1
// one wave per dst node; lane owns float2 of features (j0=2*lane); head = lane>>4.
__global__ __launch_bounds__(64) void k_aggr1(
    const int* __restrict__ rowptr, const int* __restrict__ counts,
    const int* __restrict__ csr,
    const float* __restrict__ praw, const float* __restrict__ rinv,
    const float* __restrict__ h, const float* __restrict__ b,
    float* __restrict__ out, int N) {
  const int d = blockIdx.x;
  if (d >= N) return;
  const int lane = threadIdx.x;
  const int head = lane >> 4;
  const int j0 = 2 * lane;
  const int row0 = rowptr[d], deg = counts[d];
  float ax = 0.f, ay = 0.f;
  int i = 0;
  for (; i + 2 <= deg; i += 2) {
    const int s0 = __builtin_amdgcn_readfirstlane(csr[row0 + i]);
    const int s1 = __builtin_amdgcn_readfirstlane(csr[row0 + i + 1]);
    const float p0 = praw[(size_t)(row0 + i) * NH1 + head];
    const float p1 = praw[(size_t)(row0 + i + 1) * NH1 + head];
    const float2 h0 = *(const float2*)(h + (size_t)s0 * HID + j0);
    const float2 h1v = *(const float2*)(h + (size_t)s1 * HID + j0);
    ax += p0 * h0.x;  ay += p0 * h0.y;
    ax += p1 * h1v.x; ay += p1 * h1v.y;
  }
  if (i < deg) {
    const int s0 = __builtin_amdgcn_readfirstlane(csr[row0 + i]);
    const float p0 = praw[(size_t)(row0 + i) * NH1 + head];
    const float2 h0 = *(const float2*)(h + (size_t)s0 * HID + j0);
    ax += p0 * h0.x;  ay += p0 * h0.y;
  }
  const float r = rinv[d * NH1 + head];
  const float2 bv = *(const float2*)(b + j0);
  float2 o;
  o.x = eluf(ax * r + bv.x);
  o.y = eluf(ay * r + bv.y);
  *(float2*)(out + (size_t)d * HID + j0) = o;
}

// ---------------------------------------------------------------- weighted gather, layer 2
// one wave per dst node; lane owns feature lane (64 feats).
__global__ __launch_bounds__(64) void k_aggr2(
    const int* __restrict__ rowptr, const int* __restrict__ counts,
    const int* __restrict__ csr,
    const float* __restrict__ praw, const float* __restrict__ rinv,
    const float* __restrict__ h, const float* __restrict__ b,
    float* __restrict__ out, int N) {
  const int d = blockIdx.x;
  if (d >= N) return;
  const int lane = threadIdx.x;
  const int row0 = rowptr[d], deg = counts[d];
  float acc = 0.f;
  int i = 0;
  for (; i + 2 <= deg; i += 2) {
    const int s0 = __builtin_amdgcn_readfirstlane(csr[row0 + i]);
    const int s1 = __builtin_amdgcn_readfirstlane(csr[row0 + i + 1]);
    const float p0 = __uint_as_float(__builtin_amdgcn_readfirstlane(__float_as_uint(praw[row0 + i])));
    const float p1 = __uint_as_float(__builtin_amdgcn_readfirstlane(__float_as_uint(praw[row0 + i + 1])));
    const float h0 = h[(size_t)s0 * OUTF + lane];
    const float h1v = h[(size_t)s1 * OUTF + lane];
    acc += p0 * h0;
    acc += p1 * h1v;
  }
  if (i < deg) {
    const int s0 = __builtin_amdgcn_readfirstlane(csr[row0 + i]);
    const float p0 = __uint_as_float(__builtin_amdgcn_readfirstlane(__float_as_uint(praw[row0 + i])));
    acc += p0 * h[(size_t)s0 * OUTF + lane];
  }
  out[(size_t)d * OUTF + lane] = acc * rinv[d] + b[lane];
}

// ---------------------------------------------------------------- launch
extern "C" void kernel_launch(void* const* d_in, const int* in_sizes, int n_in,
                              void* d_out, int out_size, void* d_ws, size_t ws_size,
                              hipStream_t stream) {
  const float* x   = (const float*)d_in[0];
  const int*   ei  = (const int*)d_in[1];
  const float* W1  = (const float*)d_in[2];
  const float* a1s = (const float*)d_in[3];
  const float* a1d = (const float*)d_in[4];
  const float* b1  = (const float*)d_in[5];
  const float* W2  = (const float*)d_in[6];
  const float* a2s = (const float*)d_in[7];
  const float* a2d = (const float*)d_in[8];
  const float* b2  = (const float*)d_in[9];
  float* out = (float*)d_out;

  const int N = in_sizes[0] / IN_F;
  const int E = in_sizes[1] / 2;
  const int ET = E + N;
  const int* srcI = ei;
  const int* dstI = ei + E;
  const int nb = (N + 255) / 256;

  // workspace layout (ints first, then 16B-aligned floats)
  int* rowptr  = (int*)d_ws;                  // N
  int* counts  = rowptr + N;                  // N
  int* cursor  = counts + N;                  // N
  int* partial = cursor + N;                  // nb (<=1024)
  int* csr     = partial + 1024;              // ET
  size_t int_end = (size_t)(3 * N + 1024 + ET);
  int_end = (int_end + 3) & ~(size_t)3;       // 16B alignment
  float* h1    = (float*)d_ws + int_end;      // N*128 (reused as h2: N*64)
  float* out1  = h1 + (size_t)N * HID;        // N*128 (post-ELU)
  float* al1s_ = out1 + (size_t)N * HID;      // N*4
  float* al1d_ = al1s_ + (size_t)N * NH1;     // N*4
  float* al2s_ = al1d_ + (size_t)N * NH1;     // N
  float* al2d_ = al2s_ + N;                   // N
  float* rinv1 = al2d_ + N;                   // N*4
  float* rinv2 = rinv1 + (size_t)N * NH1;     // N
  float* praw  = rinv2 + N;                   // ET*4 (layer1) / ET (layer2, aliased)

  // CSR build (shared by both layers)
  k_counts_init<<<nb, 256, 0, stream>>>(counts, N);
  k_count<<<(E + 255) / 256, 256, 0, stream>>>(dstI, E, counts);
  k_scan_a<<<nb, 256, 0, stream>>>(counts, partial, N);
  k_scan_b<<<1, 1024, 0, stream>>>(partial, nb);
  k_scan_c<<<nb, 256, 0, stream>>>(counts, partial, rowptr, cursor, csr, N);
  k_scatter<<<(E + 255) / 256, 256, 0, stream>>>(srcI, dstI, E, cursor, csr);

  // layer 1
  k_gemm1<<<512, 256, 0, stream>>>(x, W1, a1s, a1d, h1, al1s_, al1d_, N);
  k_att1<<<N, 64, 0, stream>>>(rowptr, counts, csr, al1s_, al1d_, praw, rinv1, N);
  k_aggr1<<<N, 64, 0, stream>>>(rowptr, counts, csr, praw, rinv1, h1, b1, out1, N);

  // layer 2 (h2 aliases h1's buffer; praw reused as scalar array)
  k_gemm2<<<512, 256, 0, stream>>>(out1, W2, a2s, a2d, h1, al2s_, al2d_, N);
  k_att2<<<N, 64, 0, stream>>>(rowptr, counts, csr, al2s_, al2d_, praw, rinv2, N);
  k_aggr2<<<N, 64, 0, stream>>>(rowptr, counts, csr, praw, rinv2, h1, b2, out, N);
}

// Round 6
// 340.252 us; speedup vs baseline: 10.4319x; 1.0784x over previous
//
#include <hip/hip_runtime.h>
#include <hip/hip_bf16.h>
#include <cstdint>
#include <cstddef>

#define IN_F 128
#define HID 128
#define NH1 4
#define OUTF 64

__device__ __forceinline__ float lrelu(float v) { return v > 0.f ? v : 0.2f * v; }
__device__ __forceinline__ float eluf(float v) { return v > 0.f ? v : (__expf(v) - 1.f); }

// ---------------------------------------------------------------- CSR build
__global__ void k_counts_init(int* __restrict__ counts, int N) {
  int t = blockIdx.x * blockDim.x + threadIdx.x;
  if (t < N) counts[t] = 1;  // self-loop
}

__global__ void k_count(const int* __restrict__ dst, int E, int* __restrict__ counts) {
  int e = blockIdx.x * blockDim.x + threadIdx.x;
  if (e < E) atomicAdd(counts + dst[e], 1);
}

// hierarchical scan, phase A: per-block reduction of 256 counts
__global__ __launch_bounds__(256) void k_scan_a(const int* __restrict__ counts,
                                                int* __restrict__ partial, int N) {
  __shared__ int red[256];
  const int i = blockIdx.x * 256 + threadIdx.x;
  red[threadIdx.x] = (i < N) ? counts[i] : 0;
  __syncthreads();
  #pragma unroll
  for (int off = 128; off > 0; off >>= 1) {
    if (threadIdx.x < off) red[threadIdx.x] += red[threadIdx.x + off];
    __syncthreads();
  }
  if (threadIdx.x == 0) partial[blockIdx.x] = red[0];
}

// phase B: single small block scans the <=1024 block partials (exclusive, in place)
__global__ __launch_bounds__(1024) void k_scan_b(int* __restrict__ partial, int nb) {
  __shared__ int sm[1024];
  const int t = threadIdx.x;
  const int v = (t < nb) ? partial[t] : 0;
  sm[t] = v;
  __syncthreads();
  #pragma unroll
  for (int off = 1; off < 1024; off <<= 1) {
    const int u = (t >= off) ? sm[t - off] : 0;
    __syncthreads();
    sm[t] += u;
    __syncthreads();
  }
  if (t < nb) partial[t] = sm[t] - v;  // exclusive
}

// phase C: per-block exclusive scan + global offset; emit rowptr/cursor/self-loop
__global__ __launch_bounds__(256) void k_scan_c(const int* __restrict__ counts,
                                                const int* __restrict__ partial,
                                                int* __restrict__ rowptr,
                                                int* __restrict__ cursor,
                                                int* __restrict__ csr, int N) {
  __shared__ int sm[256];
  const int i = blockIdx.x * 256 + threadIdx.x;
  const int t = threadIdx.x;
  const int v = (i < N) ? counts[i] : 0;
  sm[t] = v;
  __syncthreads();
  #pragma unroll
  for (int off = 1; off < 256; off <<= 1) {
    const int u = (t >= off) ? sm[t - off] : 0;
    __syncthreads();
    sm[t] += u;
    __syncthreads();
  }
  if (i < N) {
    const int e = partial[blockIdx.x] + sm[t] - v;
    rowptr[i] = e;
    cursor[i] = e + 1;   // slot 0 reserved for self-loop
    csr[e] = i;          // self-loop src = i
  }
}

__global__ void k_scatter(const int* __restrict__ src, const int* __restrict__ dst, int E,
                          int* __restrict__ cursor, int* __restrict__ csr) {
  int e = blockIdx.x * blockDim.x + threadIdx.x;
  if (e < E) {
    int d = dst[e];
    int pos = atomicAdd(cursor + d, 1);
    csr[pos] = src[e];
  }
}

// ---------------------------------------------------------------- layer-1 GEMM + attention dots
// W1 in LDS once (64 KB). Lane owns column PAIR (2*lane, 2*lane+1) -> ds_read_b64.
// 8 rows per wave -> 2048 FMA : 128 LDS-b64 per tile. x rows via wave-uniform loads.
__global__ __launch_bounds__(256) void k_gemm1(
    const float* __restrict__ x, const float* __restrict__ W,
    const float* __restrict__ a_s, const float* __restrict__ a_d,
    float* __restrict__ h, float* __restrict__ als, float* __restrict__ ald, int N) {
  __shared__ float Ws[IN_F * HID];  // 64 KB
  const int wave = threadIdx.x >> 6, lane = threadIdx.x & 63;
  for (int i = threadIdx.x * 4; i < IN_F * HID; i += 256 * 4)
    *(float4*)(Ws + i) = *(const float4*)(W + i);
  __syncthreads();
  const int c0 = 2 * lane;
  const float as0 = a_s[c0], as1 = a_s[c0 + 1];
  const float ad0 = a_d[c0], ad1 = a_d[c0 + 1];
  const int stride = gridDim.x * 32;  // 4 waves * 8 rows
  for (int base = blockIdx.x * 32 + wave * 8; base < N; base += stride) {
    const int r0 = __builtin_amdgcn_readfirstlane(base);
    const float* __restrict__ xr = x + (size_t)r0 * IN_F;
    float accx[8] = {0,0,0,0,0,0,0,0}, accy[8] = {0,0,0,0,0,0,0,0};
    const int vr = min(8, N - r0);
    if (vr == 8) {
      for (int k = 0; k < IN_F; k += 4) {
        float4 xq[8];
        #pragma unroll
        for (int ri = 0; ri < 8; ++ri) xq[ri] = *(const float4*)(xr + ri * IN_F + k);
        #pragma unroll
        for (int kk = 0; kk < 4; ++kk) {
          const float2 w = *(const float2*)(Ws + (k + kk) * HID + c0);
          #pragma unroll
          for (int ri = 0; ri < 8; ++ri) {
            const float xv = ((const float*)&xq[ri])[kk];
            accx[ri] += xv * w.x;
            accy[ri] += xv * w.y;
          }
        }
      }
    } else {
      for (int k = 0; k < IN_F; ++k) {
        const float2 w = *(const float2*)(Ws + k * HID + c0);
        for (int ri = 0; ri < vr; ++ri) {
          const float xv = xr[ri * IN_F + k];
          accx[ri] += xv * w.x;
          accy[ri] += xv * w.y;
        }
      }
    }
    #pragma unroll
    for (int ri = 0; ri < 8; ++ri) {
      if (ri < vr) {
        float2 o; o.x = accx[ri]; o.y = accy[ri];
        *(float2*)(h + (size_t)(r0 + ri) * HID + c0) = o;
      }
    }
    #pragma unroll
    for (int ri = 0; ri < 8; ++ri) {
      float ps = accx[ri] * as0 + accy[ri] * as1;
      float pd = accx[ri] * ad0 + accy[ri] * ad1;
      #pragma unroll
      for (int mk = 1; mk <= 8; mk <<= 1) {
        ps += __shfl_xor(ps, mk, 16);
        pd += __shfl_xor(pd, mk, 16);
      }
      if (ri < vr && (lane & 15) == 0) {
        const int head = lane >> 4;
        als[(r0 + ri) * NH1 + head] = ps;
        ald[(r0 + ri) * NH1 + head] = pd;
      }
    }
  }
}

// ---------------------------------------------------------------- layer-2 GEMM
// W2 in LDS once (32 KB). Lane owns one of 64 cols; 8 rows per wave.
__global__ __launch_bounds__(256) void k_gemm2(
    const float* __restrict__ hin, const float* __restrict__ W,
    const float* __restrict__ a_s, const float* __restrict__ a_d,
    float* __restrict__ h, float* __restrict__ als, float* __restrict__ ald, int N) {
  __shared__ float Ws[HID * OUTF];  // 32 KB
  const int wave = threadIdx.x >> 6, lane = threadIdx.x & 63;
  for (int i = threadIdx.x * 4; i < HID * OUTF; i += 256 * 4)
    *(float4*)(Ws + i) = *(const float4*)(W + i);
  __syncthreads();
  const float asj = a_s[lane], adj = a_d[lane];
  const int stride = gridDim.x * 32;
  for (int base = blockIdx.x * 32 + wave * 8; base < N; base += stride) {
    const int r0 = __builtin_amdgcn_readfirstlane(base);
    const float* __restrict__ xr = hin + (size_t)r0 * HID;
    float acc[8] = {0,0,0,0,0,0,0,0};
    const int vr = min(8, N - r0);
    if (vr == 8) {
      for (int k = 0; k < HID; k += 4) {
        float4 xq[8];
        #pragma unroll
        for (int ri = 0; ri < 8; ++ri) xq[ri] = *(const float4*)(xr + ri * HID + k);
        #pragma unroll
        for (int kk = 0; kk < 4; ++kk) {
          const float w0 = Ws[(k + kk) * OUTF + lane];
          #pragma unroll
          for (int ri = 0; ri < 8; ++ri) acc[ri] += ((const float*)&xq[ri])[kk] * w0;
        }
      }
    } else {
      for (int k = 0; k < HID; ++k) {
        const float w0 = Ws[k * OUTF + lane];
        for (int ri = 0; ri < vr; ++ri) acc[ri] += xr[ri * HID + k] * w0;
      }
    }
    #pragma unroll
    for (int ri = 0; ri < 8; ++ri) {
      if (ri < vr) h[(size_t)(r0 + ri) * OUTF + lane] = acc[ri];
    }
    #pragma unroll
    for (int ri = 0; ri < 8; ++ri) {
      float ps = acc[ri] * asj, pd = acc[ri] * adj;
      #pragma unroll
      for (int mk = 1; mk <= 32; mk <<= 1) {
        ps += __shfl_xor(ps, mk, 64); pd += __shfl_xor(pd, mk, 64);
      }
      if (ri < vr && lane == 0) { als[r0 + ri] = ps; ald[r0 + ri] = pd; }
    }
  }
}

// ---------------------------------------------------------------- attention softmax, layer 1
// one wave per dst node; lane = slot*4+head (16 edge-slots x 4 heads).
__global__ __launch_bounds__(64) void k_att1(
    const int* __restrict__ rowptr, const int* __restrict__ counts,
    const int* __restrict__ csr,
    const float* __restrict__ als, const float* __restrict__ ald,
    float* __restrict__ praw, float* __restrict__ rinv, int N) {
  const int d = blockIdx.x;
  if (d >= N) return;
  const int lane = threadIdx.x;
  const int slot = lane >> 2, head = lane & 3;
  const int row0 = rowptr[d], deg = counts[d];
  const float aldh = ald[d * NH1 + head];
  float vmax = -1e30f;
  for (int i = slot; i < deg; i += 16) {
    const int s = csr[row0 + i];
    vmax = fmaxf(vmax, lrelu(als[s * NH1 + head] + aldh));
  }
  #pragma unroll
  for (int mk = 4; mk <= 32; mk <<= 1) vmax = fmaxf(vmax, __shfl_xor(vmax, mk, 64));
  float sum = 0.f;
  for (int i = slot; i < deg; i += 16) {
    const int s = csr[row0 + i];
    const float v = lrelu(als[s * NH1 + head] + aldh);
    const float p = __expf(v - vmax);
    sum += p;
    praw[(size_t)(row0 + i) * NH1 + head] = p;
  }
  #pragma unroll
  for (int mk = 4; mk <= 32; mk <<= 1) sum += __shfl_xor(sum, mk, 64);
  if (slot == 0) rinv[d * NH1 + head] = 1.f / (sum + 1e-16f);
}

// ---------------------------------------------------------------- attention softmax, layer 2 (H=1)
__global__ __launch_bounds__(64) void k_att2(
    const int* __restrict__ rowptr, const int* __restrict__ counts,
    const int* __restrict__ csr,
    const float* __restrict__ als, const float* __restrict__ ald,
    float* __restrict__ praw, float* __restrict__ rinv, int N) {
  const int d = blockIdx.x;
  if (d >= N) return;
  const int lane = threadIdx.x;
  const int row0 = rowptr[d], deg = counts[d];
  const float aldd = ald[d];
  float vmax = -1e30f;
  for (int i = lane; i < deg; i += 64) {
    const int s = csr[row0 + i];
    vmax = fmaxf(vmax, lrelu(als[s] + aldd));
  }
  #pragma unroll
  for (int mk = 1; mk <= 32; mk <<= 1) vmax = fmaxf(vmax, __shfl_xor(vmax, mk, 64));
  float sum = 0.f;
  for (int i = lane; i < deg; i += 64) {
    const int s = csr[row0 + i];
    const float p = __expf(lrelu(als[s] + aldd) - vmax);
    sum += p;
    praw[row0 + i] = p;
  }
  #pragma unroll
  for (int mk = 1; mk <= 32; mk <<= 1) sum += __shfl_xor(sum, mk, 64);
  if (lane == 0) rinv[d] = 1.f / (sum + 1e-16f);
}

// ---------------------------------------------------------------- weighted gather, layer 1
// one wave per dst node; lane owns float2 of features (j0=2*lane); head = lane>>4.
__global__ __launch_bounds__(64) void k_aggr1(
    const int* __restrict__ rowptr, const int* __restrict__ counts,
    const int* __restrict__ csr,
    const float* __restrict__ praw, const float* __restrict__ rinv,
    const float* __restrict__ h, const float* __restrict__ b,
    float* __restrict__ out, int N) {
  const int d = blockIdx.x;
  if (d >= N) return;
  const int lane = threadIdx.x;
  const int head = lane >> 4;
  const int j0 = 2 * lane;
  const int row0 = rowptr[d], deg = counts[d];
  float ax = 0.f, ay = 0.f;
  int i = 0;
  for (; i + 2 <= deg; i += 2) {
    const int s0 = __builtin_amdgcn_readfirstlane(csr[row0 + i]);
    const int s1 = __builtin_amdgcn_readfirstlane(csr[row0 + i + 1]);
    const float p0 = praw[(size_t)(row0 + i) * NH1 + head];
    const float p1 = praw[(size_t)(row0 + i + 1) * NH1 + head];
    const float2 h0 = *(const float2*)(h + (size_t)s0 * HID + j0);
    const float2 h1v = *(const float2*)(h + (size_t)s1 * HID + j0);
    ax += p0 * h0.x;  ay += p0 * h0.y;
    ax += p1 * h1v.x; ay += p1 * h1v.y;
  }
  if (i < deg) {
    const int s0 = __builtin_amdgcn_readfirstlane(csr[row0 + i]);
    const float p0 = praw[(size_t)(row0 + i) * NH1 + head];
    const float2 h0 = *(const float2*)(h + (size_t)s0 * HID + j0);
    ax += p0 * h0.x;  ay += p0 * h0.y;
  }
  const float r = rinv[d * NH1 + head];
  const float2 bv = *(const float2*)(b + j0);
  float2 o;
  o.x = eluf(ax * r + bv.x);
  o.y = eluf(ay * r + bv.y);
  *(float2*)(out + (size_t)d * HID + j0) = o;
}

// ---------------------------------------------------------------- weighted gather, layer 2
__global__ __launch_bounds__(64) void k_aggr2(
    const int* __restrict__ rowptr, const int* __restrict__ counts,
    const int* __restrict__ csr,
    const float* __restrict__ praw, const float* __restrict__ rinv,
    const float* __restrict__ h, const float* __restrict__ b,
    float* __restrict__ out, int N) {
  const int d = blockIdx.x;
  if (d >= N) return;
  const int lane = threadIdx.x;
  const int row0 = rowptr[d], deg = counts[d];
  float acc = 0.f;
  int i = 0;
  for (; i + 2 <= deg; i += 2) {
    const int s0 = __builtin_amdgcn_readfirstlane(csr[row0 + i]);
    const int s1 = __builtin_amdgcn_readfirstlane(csr[row0 + i + 1]);
    const float p0 = __uint_as_float(__builtin_amdgcn_readfirstlane(__float_as_uint(praw[row0 + i])));
    const float p1 = __uint_as_float(__builtin_amdgcn_readfirstlane(__float_as_uint(praw[row0 + i + 1])));
    const float h0 = h[(size_t)s0 * OUTF + lane];
    const float h1v = h[(size_t)s1 * OUTF + lane];
    acc += p0 * h0;
    acc += p1 * h1v;
  }
  if (i < deg) {
    const int s0 = __builtin_amdgcn_readfirstlane(csr[row0 + i]);
    const float p0 = __uint_as_float(__builtin_amdgcn_readfirstlane(__float_as_uint(praw[row0 + i])));
    acc += p0 * h[(size_t)s0 * OUTF + lane];
  }
  out[(size_t)d * OUTF + lane] = acc * rinv[d] + b[lane];
}

// ---------------------------------------------------------------- launch
extern "C" void kernel_launch(void* const* d_in, const int* in_sizes, int n_in,
                              void* d_out, int out_size, void* d_ws, size_t ws_size,
                              hipStream_t stream) {
  const float* x   = (const float*)d_in[0];
  const int*   ei  = (const int*)d_in[1];
  const float* W1  = (const float*)d_in[2];
  const float* a1s = (const float*)d_in[3];
  const float* a1d = (const float*)d_in[4];
  const float* b1  = (const float*)d_in[5];
  const float* W2  = (const float*)d_in[6];
  const float* a2s = (const float*)d_in[7];
  const float* a2d = (const float*)d_in[8];
  const float* b2  = (const float*)d_in[9];
  float* out = (float*)d_out;

  const int N = in_sizes[0] / IN_F;
  const int E = in_sizes[1] / 2;
  const int ET = E + N;
  const int* srcI = ei;
  const int* dstI = ei + E;
  const int nb = (N + 255) / 256;

  // workspace layout (ints first, then 16B-aligned floats)
  int* rowptr  = (int*)d_ws;                  // N
  int* counts  = rowptr + N;                  // N
  int* cursor  = counts + N;                  // N
  int* partial = cursor + N;                  // nb (<=1024)
  int* csr     = partial + 1024;              // ET
  size_t int_end = (size_t)(3 * N + 1024 + ET);
  int_end = (int_end + 3) & ~(size_t)3;       // 16B alignment
  float* h1    = (float*)d_ws + int_end;      // N*128 (reused as h2: N*64)
  float* out1  = h1 + (size_t)N * HID;        // N*128 (post-ELU)
  float* al1s_ = out1 + (size_t)N * HID;      // N*4
  float* al1d_ = al1s_ + (size_t)N * NH1;     // N*4
  float* al2s_ = al1d_ + (size_t)N * NH1;     // N
  float* al2d_ = al2s_ + N;                   // N
  float* rinv1 = al2d_ + N;                   // N*4
  float* rinv2 = rinv1 + (size_t)N * NH1;     // N
  float* praw  = rinv2 + N;                   // ET*4 (layer1) / ET (layer2, aliased)

  // CSR build (shared by both layers)
  k_counts_init<<<nb, 256, 0, stream>>>(counts, N);
  k_count<<<(E + 255) / 256, 256, 0, stream>>>(dstI, E, counts);
  k_scan_a<<<nb, 256, 0, stream>>>(counts, partial, N);
  k_scan_b<<<1, 1024, 0, stream>>>(partial, nb);
  k_scan_c<<<nb, 256, 0, stream>>>(counts, partial, rowptr, cursor, csr, N);
  k_scatter<<<(E + 255) / 256, 256, 0, stream>>>(srcI, dstI, E, cursor, csr);

  // layer 1
  k_gemm1<<<512, 256, 0, stream>>>(x, W1, a1s, a1d, h1, al1s_, al1d_, N);
  k_att1<<<N, 64, 0, stream>>>(rowptr, counts, csr, al1s_, al1d_, praw, rinv1, N);
  k_aggr1<<<N, 64, 0, stream>>>(rowptr, counts, csr, praw, rinv1, h1, b1, out1, N);

  // layer 2 (h2 aliases h1's buffer; praw reused as scalar array)
  k_gemm2<<<512, 256, 0, stream>>>(out1, W2, a2s, a2d, h1, al2s_, al2d_, N);
  k_att2<<<N, 64, 0, stream>>>(rowptr, counts, csr, al2s_, al2d_, praw, rinv2, N);
  k_aggr2<<<N, 64, 0, stream>>>(rowptr, counts, csr, praw, rinv2, h1, b2, out, N);
}

// Round 7
// 282.028 us; speedup vs baseline: 12.5856x; 1.2064x over previous
//
#include <hip/hip_runtime.h>
#include <hip/hip_bf16.h>
#include <cstdint>
#include <cstddef>

#define IN_F 128
#define HID 128
#define NH1 4
#define OUTF 64

__device__ __forceinline__ float lrelu(float v) { return v > 0.f ? v : 0.2f * v; }
__device__ __forceinline__ float eluf(float v) { return v > 0.f ? v : (__expf(v) - 1.f); }

// ---------------------------------------------------------------- CSR build
__global__ void k_counts_init(int* __restrict__ counts, int N) {
  int t = blockIdx.x * blockDim.x + threadIdx.x;
  if (t < N) counts[t] = 1;  // self-loop
}

__global__ void k_count(const int* __restrict__ dst, int E, int* __restrict__ counts) {
  int e = blockIdx.x * blockDim.x + threadIdx.x;
  if (e < E) atomicAdd(counts + dst[e], 1);
}

__global__ __launch_bounds__(256) void k_scan_a(const int* __restrict__ counts,
                                                int* __restrict__ partial, int N) {
  __shared__ int red[256];
  const int i = blockIdx.x * 256 + threadIdx.x;
  red[threadIdx.x] = (i < N) ? counts[i] : 0;
  __syncthreads();
  #pragma unroll
  for (int off = 128; off > 0; off >>= 1) {
    if (threadIdx.x < off) red[threadIdx.x] += red[threadIdx.x + off];
    __syncthreads();
  }
  if (threadIdx.x == 0) partial[blockIdx.x] = red[0];
}

__global__ __launch_bounds__(1024) void k_scan_b(int* __restrict__ partial, int nb) {
  __shared__ int sm[1024];
  const int t = threadIdx.x;
  const int v = (t < nb) ? partial[t] : 0;
  sm[t] = v;
  __syncthreads();
  #pragma unroll
  for (int off = 1; off < 1024; off <<= 1) {
    const int u = (t >= off) ? sm[t - off] : 0;
    __syncthreads();
    sm[t] += u;
    __syncthreads();
  }
  if (t < nb) partial[t] = sm[t] - v;  // exclusive
}

__global__ __launch_bounds__(256) void k_scan_c(const int* __restrict__ counts,
                                                const int* __restrict__ partial,
                                                int* __restrict__ rowptr,
                                                int* __restrict__ cursor,
                                                int* __restrict__ csr, int N) {
  __shared__ int sm[256];
  const int i = blockIdx.x * 256 + threadIdx.x;
  const int t = threadIdx.x;
  const int v = (i < N) ? counts[i] : 0;
  sm[t] = v;
  __syncthreads();
  #pragma unroll
  for (int off = 1; off < 256; off <<= 1) {
    const int u = (t >= off) ? sm[t - off] : 0;
    __syncthreads();
    sm[t] += u;
    __syncthreads();
  }
  if (i < N) {
    const int e = partial[blockIdx.x] + sm[t] - v;
    rowptr[i] = e;
    cursor[i] = e + 1;   // slot 0 reserved for self-loop
    csr[e] = i;          // self-loop src = i
  }
}

__global__ void k_scatter(const int* __restrict__ src, const int* __restrict__ dst, int E,
                          int* __restrict__ cursor, int* __restrict__ csr) {
  int e = blockIdx.x * blockDim.x + threadIdx.x;
  if (e < E) {
    int d = dst[e];
    int pos = atomicAdd(cursor + d, 1);
    csr[pos] = src[e];
  }
}

// ---------------------------------------------------------------- layer-1 GEMM + attention dots
// W1 in LDS (64 KB) + 32-row x tile in LDS (16 KB) -> inner loop is PURE DS
// (uniform ds_read_b128 x broadcasts + ds_read_b64 W), no SMEM/VMEM mixing.
// Lane owns col pair (2*lane); 8 rows/wave, 32 rows/block.
__global__ __launch_bounds__(256) void k_gemm1(
    const float* __restrict__ x, const float* __restrict__ W,
    const float* __restrict__ a_s, const float* __restrict__ a_d,
    float* __restrict__ h, float* __restrict__ als, float* __restrict__ ald, int N) {
  __shared__ float Ws[IN_F * HID];   // 64 KB
  __shared__ float xs[32 * IN_F];    // 16 KB
  const int wave = threadIdx.x >> 6, lane = threadIdx.x & 63;
  for (int i = threadIdx.x * 4; i < IN_F * HID; i += 1024)
    *(float4*)(Ws + i) = *(const float4*)(W + i);
  const int c0 = 2 * lane;
  const float as0 = a_s[c0], as1 = a_s[c0 + 1];
  const float ad0 = a_d[c0], ad1 = a_d[c0 + 1];
  const int stride = gridDim.x * 32;
  for (int base = blockIdx.x * 32; base < N; base += stride) {
    __syncthreads();
    // stage 32 rows of x (coalesced float4 per lane; zero-pad tail rows)
    #pragma unroll
    for (int f = threadIdx.x; f < 32 * (IN_F / 4); f += 256) {
      const int row = f >> 5, c4 = (f & 31) * 4;
      const int gr = base + row;
      float4 v = make_float4(0.f, 0.f, 0.f, 0.f);
      if (gr < N) v = *(const float4*)(x + (size_t)gr * IN_F + c4);
      *(float4*)(xs + row * IN_F + c4) = v;
    }
    __syncthreads();
    const int r0 = base + wave * 8;
    float accx[8] = {0,0,0,0,0,0,0,0}, accy[8] = {0,0,0,0,0,0,0,0};
    for (int k = 0; k < IN_F; k += 4) {
      float4 xq[8];
      #pragma unroll
      for (int ri = 0; ri < 8; ++ri)
        xq[ri] = *(const float4*)(xs + (wave * 8 + ri) * IN_F + k);
      #pragma unroll
      for (int kk = 0; kk < 4; ++kk) {
        const float2 w = *(const float2*)(Ws + (k + kk) * HID + c0);
        #pragma unroll
        for (int ri = 0; ri < 8; ++ri) {
          const float xv = ((const float*)&xq[ri])[kk];
          accx[ri] += xv * w.x;
          accy[ri] += xv * w.y;
        }
      }
    }
    const int vr = min(8, N - r0);
    #pragma unroll
    for (int ri = 0; ri < 8; ++ri) {
      if (ri < vr) {
        float2 o; o.x = accx[ri]; o.y = accy[ri];
        *(float2*)(h + (size_t)(r0 + ri) * HID + c0) = o;
      }
    }
    #pragma unroll
    for (int ri = 0; ri < 8; ++ri) {
      float ps = accx[ri] * as0 + accy[ri] * as1;
      float pd = accx[ri] * ad0 + accy[ri] * ad1;
      #pragma unroll
      for (int mk = 1; mk <= 8; mk <<= 1) {
        ps += __shfl_xor(ps, mk, 16);
        pd += __shfl_xor(pd, mk, 16);
      }
      if (ri < vr && (lane & 15) == 0) {
        const int head = lane >> 4;
        als[(r0 + ri) * NH1 + head] = ps;
        ald[(r0 + ri) * NH1 + head] = pd;
      }
    }
  }
}

// ---------------------------------------------------------------- layer-2 GEMM
// W2 (32 KB) + x tile (16 KB) in LDS; pure-DS inner loop.
// Lane = (k-half, col-pair): c0 = 2*(lane&31), k range [kb, kb+64); halves
// combined via shfl_xor(32). 8 rows/wave, 32 rows/block.
__global__ __launch_bounds__(256) void k_gemm2(
    const float* __restrict__ hin, const float* __restrict__ W,
    const float* __restrict__ a_s, const float* __restrict__ a_d,
    float* __restrict__ h, float* __restrict__ als, float* __restrict__ ald, int N) {
  __shared__ float Ws[HID * OUTF];   // 32 KB
  __shared__ float xs[32 * HID];     // 16 KB
  const int wave = threadIdx.x >> 6, lane = threadIdx.x & 63;
  for (int i = threadIdx.x * 4; i < HID * OUTF; i += 1024)
    *(float4*)(Ws + i) = *(const float4*)(W + i);
  const int c0 = 2 * (lane & 31);
  const int kb = (lane >> 5) * 64;
  const float as0 = a_s[c0], as1 = a_s[c0 + 1];
  const float ad0 = a_d[c0], ad1 = a_d[c0 + 1];
  const int stride = gridDim.x * 32;
  for (int base = blockIdx.x * 32; base < N; base += stride) {
    __syncthreads();
    #pragma unroll
    for (int f = threadIdx.x; f < 32 * (HID / 4); f += 256) {
      const int row = f >> 5, c4 = (f & 31) * 4;
      const int gr = base + row;
      float4 v = make_float4(0.f, 0.f, 0.f, 0.f);
      if (gr < N) v = *(const float4*)(hin + (size_t)gr * HID + c4);
      *(float4*)(xs + row * HID + c4) = v;
    }
    __syncthreads();
    const int r0 = base + wave * 8;
    float accx[8] = {0,0,0,0,0,0,0,0}, accy[8] = {0,0,0,0,0,0,0,0};
    for (int k = 0; k < 64; k += 4) {
      float4 xq[8];
      #pragma unroll
      for (int ri = 0; ri < 8; ++ri)
        xq[ri] = *(const float4*)(xs + (wave * 8 + ri) * HID + kb + k);
      #pragma unroll
      for (int kk = 0; kk < 4; ++kk) {
        const float2 w = *(const float2*)(Ws + (kb + k + kk) * OUTF + c0);
        #pragma unroll
        for (int ri = 0; ri < 8; ++ri) {
          const float xv = ((const float*)&xq[ri])[kk];
          accx[ri] += xv * w.x;
          accy[ri] += xv * w.y;
        }
      }
    }
    // combine k-halves (both halves end with the full sum)
    #pragma unroll
    for (int ri = 0; ri < 8; ++ri) {
      accx[ri] += __shfl_xor(accx[ri], 32, 64);
      accy[ri] += __shfl_xor(accy[ri], 32, 64);
    }
    const int vr = min(8, N - r0);
    #pragma unroll
    for (int ri = 0; ri < 8; ++ri) {
      if (ri < vr && lane < 32) {
        float2 o; o.x = accx[ri]; o.y = accy[ri];
        *(float2*)(h + (size_t)(r0 + ri) * OUTF + c0) = o;
      }
    }
    #pragma unroll
    for (int ri = 0; ri < 8; ++ri) {
      float ps = accx[ri] * as0 + accy[ri] * as1;
      float pd = accx[ri] * ad0 + accy[ri] * ad1;
      #pragma unroll
      for (int mk = 1; mk <= 16; mk <<= 1) {
        ps += __shfl_xor(ps, mk, 32);
        pd += __shfl_xor(pd, mk, 32);
      }
      if (ri < vr && lane == 0) { als[r0 + ri] = ps; ald[r0 + ri] = pd; }
    }
  }
}

// ---------------------------------------------------------------- fused softmax+gather, layer 1
// one wave per dst node. Pass A: per-head max (lane = slot*4+headA, shfl_xor
// reduce). Pass B: lane owns float2 features (j0=2*lane), head=lane>>4;
// exp + h-row gather + FMA. csr chunk staged in LDS (coalesced).
#define CHNK 256
__global__ __launch_bounds__(64) void k_aggr1(
    const int* __restrict__ rowptr, const int* __restrict__ counts,
    const int* __restrict__ csr,
    const float* __restrict__ als, const float* __restrict__ ald,
    const float* __restrict__ h, const float* __restrict__ b,
    float* __restrict__ out, int N) {
  __shared__ int sbuf[CHNK];
  const int d = blockIdx.x;
  if (d >= N) return;
  const int lane = threadIdx.x;
  const int row0 = rowptr[d], deg = counts[d];
  // pass A: per-head max
  const int headA = lane & 3, slot = lane >> 2;
  const float aldA = ald[d * NH1 + headA];
  float m = -1e30f;
  for (int ch = 0; ch < deg; ch += CHNK) {
    const int cnt = min(CHNK, deg - ch);
    for (int i = lane; i < cnt; i += 64) sbuf[i] = csr[row0 + ch + i];
    for (int i = slot; i < cnt; i += 16) {
      const int s = sbuf[i];
      m = fmaxf(m, lrelu(als[s * NH1 + headA] + aldA));
    }
  }
  #pragma unroll
  for (int mk = 4; mk <= 32; mk <<= 1) m = fmaxf(m, __shfl_xor(m, mk, 64));
  // remap: lanes 0..3 hold heads 0..3
  const int head = lane >> 4;
  m = __shfl(m, head, 64);
  const float aldh = ald[d * NH1 + head];
  const int j0 = 2 * lane;
  // pass B: exp + weighted gather
  float sum = 0.f, ax = 0.f, ay = 0.f;
  for (int ch = 0; ch < deg; ch += CHNK) {
    const int cnt = min(CHNK, deg - ch);
    for (int i = lane; i < cnt; i += 64) sbuf[i] = csr[row0 + ch + i];
    for (int i = 0; i < cnt; ++i) {
      const int s = sbuf[i];
      const float v = lrelu(als[s * NH1 + head] + aldh);
      const float p = __expf(v - m);
      const float2 hv = *(const float2*)(h + (size_t)s * HID + j0);
      sum += p; ax += p * hv.x; ay += p * hv.y;
    }
  }
  const float r = 1.f / (sum + 1e-16f);
  float2 o;
  o.x = eluf(ax * r + b[j0]);
  o.y = eluf(ay * r + b[j0 + 1]);
  *(float2*)(out + (size_t)d * HID + j0) = o;
}

// ---------------------------------------------------------------- fused softmax+gather, layer 2 (H=1)
__global__ __launch_bounds__(64) void k_aggr2(
    const int* __restrict__ rowptr, const int* __restrict__ counts,
    const int* __restrict__ csr,
    const float* __restrict__ als, const float* __restrict__ ald,
    const float* __restrict__ h, const float* __restrict__ b,
    float* __restrict__ out, int N) {
  __shared__ int sbuf[CHNK];
  const int d = blockIdx.x;
  if (d >= N) return;
  const int lane = threadIdx.x;
  const int row0 = rowptr[d], deg = counts[d];
  const float aldd = ald[d];
  float m = -1e30f;
  for (int ch = 0; ch < deg; ch += CHNK) {
    const int cnt = min(CHNK, deg - ch);
    for (int i = lane; i < cnt; i += 64) sbuf[i] = csr[row0 + ch + i];
    for (int i = lane; i < cnt; i += 64) {
      const int s = sbuf[i];
      m = fmaxf(m, lrelu(als[s] + aldd));
    }
  }
  #pragma unroll
  for (int mk = 1; mk <= 32; mk <<= 1) m = fmaxf(m, __shfl_xor(m, mk, 64));
  float sum = 0.f, acc = 0.f;
  for (int ch = 0; ch < deg; ch += CHNK) {
    const int cnt = min(CHNK, deg - ch);
    for (int i = lane; i < cnt; i += 64) sbuf[i] = csr[row0 + ch + i];
    for (int i = 0; i < cnt; ++i) {
      const int s = sbuf[i];
      const float p = __expf(lrelu(als[s] + aldd) - m);
      sum += p;
      acc += p * h[(size_t)s * OUTF + lane];
    }
  }
  out[(size_t)d * OUTF + lane] = acc / (sum + 1e-16f) + b[lane];
}

// ---------------------------------------------------------------- launch
extern "C" void kernel_launch(void* const* d_in, const int* in_sizes, int n_in,
                              void* d_out, int out_size, void* d_ws, size_t ws_size,
                              hipStream_t stream) {
  const float* x   = (const float*)d_in[0];
  const int*   ei  = (const int*)d_in[1];
  const float* W1  = (const float*)d_in[2];
  const float* a1s = (const float*)d_in[3];
  const float* a1d = (const float*)d_in[4];
  const float* b1  = (const float*)d_in[5];
  const float* W2  = (const float*)d_in[6];
  const float* a2s = (const float*)d_in[7];
  const float* a2d = (const float*)d_in[8];
  const float* b2  = (const float*)d_in[9];
  float* out = (float*)d_out;

  const int N = in_sizes[0] / IN_F;
  const int E = in_sizes[1] / 2;
  const int ET = E + N;
  const int* srcI = ei;
  const int* dstI = ei + E;
  const int nb = (N + 255) / 256;

  // workspace layout (ints first, then 16B-aligned floats)
  int* rowptr  = (int*)d_ws;                  // N
  int* counts  = rowptr + N;                  // N
  int* cursor  = counts + N;                  // N
  int* partial = cursor + N;                  // nb (<=1024)
  int* csr     = partial + 1024;              // ET
  size_t int_end = (size_t)(3 * N + 1024 + ET);
  int_end = (int_end + 3) & ~(size_t)3;       // 16B alignment
  float* h1    = (float*)d_ws + int_end;      // N*128 (reused as h2: N*64)
  float* out1  = h1 + (size_t)N * HID;        // N*128 (post-ELU)
  float* al1s_ = out1 + (size_t)N * HID;      // N*4
  float* al1d_ = al1s_ + (size_t)N * NH1;     // N*4
  float* al2s_ = al1d_ + (size_t)N * NH1;     // N
  float* al2d_ = al2s_ + N;                   // N

  // CSR build (shared by both layers)
  k_counts_init<<<nb, 256, 0, stream>>>(counts, N);
  k_count<<<(E + 255) / 256, 256, 0, stream>>>(dstI, E, counts);
  k_scan_a<<<nb, 256, 0, stream>>>(counts, partial, N);
  k_scan_b<<<1, 1024, 0, stream>>>(partial, nb);
  k_scan_c<<<nb, 256, 0, stream>>>(counts, partial, rowptr, cursor, csr, N);
  k_scatter<<<(E + 255) / 256, 256, 0, stream>>>(srcI, dstI, E, cursor, csr);

  // layer 1
  k_gemm1<<<512, 256, 0, stream>>>(x, W1, a1s, a1d, h1, al1s_, al1d_, N);
  k_aggr1<<<N, 64, 0, stream>>>(rowptr, counts, csr, al1s_, al1d_, h1, b1, out1, N);

  // layer 2 (h2 aliases h1's buffer)
  k_gemm2<<<768, 256, 0, stream>>>(out1, W2, a2s, a2d, h1, al2s_, al2d_, N);
  k_aggr2<<<N, 64, 0, stream>>>(rowptr, counts, csr, al2s_, al2d_, h1, b2, out, N);
}